// Round 11
// baseline (1013.517 us; speedup 1.0000x reference)
//
#include <hip/hip_runtime.h>

#define DIM  1024
#define HID  2048
#define OUTD 1024
#define NE   8
#define NTOK 4096

using bf16x8 = __attribute__((ext_vector_type(8))) short;
using f32x4  = __attribute__((ext_vector_type(4))) float;

__device__ __forceinline__ unsigned short f2bf(float f) {
  unsigned int u = __builtin_bit_cast(unsigned int, f);
  u += 0x7fff + ((u >> 16) & 1);   // round-to-nearest-even
  return (unsigned short)(u >> 16);
}
__device__ __forceinline__ float b2f(unsigned short u) {
  unsigned int v = (unsigned int)u << 16;
  return __builtin_bit_cast(float, v);
}

__device__ __forceinline__ void gload16(const void* g, void* l) {
  __builtin_amdgcn_global_load_lds(
      (const __attribute__((address_space(1))) void*)g,
      (__attribute__((address_space(3))) void*)l, 16, 0, 0);
}

// ---- shared 32x32 transpose-cast tile body ----
__device__ __forceinline__ void tc_tile(const float* __restrict__ inp, int C,
                                        unsigned short* __restrict__ op, int R,
                                        int c0, int r0, float (*tile)[33],
                                        int interleave, int s) {
  int tx = threadIdx.x & 31, ty = threadIdx.x >> 5;
#pragma unroll
  for (int j = 0; j < 4; j++)
    tile[ty + j * 8][tx] = inp[(size_t)(r0 + ty + j * 8) * C + c0 + tx];
  __syncthreads();
  int c = threadIdx.x >> 3, q = threadIdx.x & 7;
  int h = c0 + c;
  int orow = interleave ? (32 * (h >> 4) + 16 * s + (h & 15)) : h;
  ushort4 u;
  u.x = f2bf(tile[q * 4 + 0][c]); u.y = f2bf(tile[q * 4 + 1][c]);
  u.z = f2bf(tile[q * 4 + 2][c]); u.w = f2bf(tile[q * 4 + 3][c]);
  *(ushort4*)&op[(size_t)orow * R + r0 + q * 4] = u;
}

// ---- merged weight transposes: one launch ----
// b < 32768: W1/W3 -> W13t (z=b>>11: e=z&7, s=z>>3)
// 32768 <= b < 49152: W2 -> W2t
// 49152 <= b < 50176: Wf -> Wft
__global__ void tcast_all_kernel(const float* __restrict__ W1, const float* __restrict__ W3,
                                 const float* __restrict__ W2, const float* __restrict__ Wf,
                                 unsigned short* __restrict__ W13t,
                                 unsigned short* __restrict__ W2t,
                                 unsigned short* __restrict__ Wft) {
  __shared__ float tile[32][33];
  int b = blockIdx.x;
  if (b < 32768) {
    int z = b >> 11, rem = b & 2047;
    int e = z & 7, s = z >> 3;
    tc_tile((s ? W3 : W1) + (size_t)e * DIM * HID, HID,
            W13t + (size_t)e * 2 * HID * DIM, DIM,
            (rem & 63) * 32, (rem >> 6) * 32, tile, 1, s);
  } else if (b < 49152) {
    int i = b - 32768;
    int z = i >> 11, rem = i & 2047;
    tc_tile(W2 + (size_t)z * HID * OUTD, OUTD, W2t + (size_t)z * OUTD * HID, HID,
            (rem & 31) * 32, (rem >> 5) * 32, tile, 0, 0);
  } else {
    int i = b - 49152;
    tc_tile(Wf, OUTD, Wft, DIM, (i & 31) * 32, (i >> 5) * 32, tile, 0, 0);
  }
}

// ---------------- gating + fused X cast + per-block histogram ----------------
__global__ __launch_bounds__(256) void gating_kernel(
    const float* __restrict__ X, const float* __restrict__ Wg,
    const float* __restrict__ bg, unsigned short* __restrict__ Xb,
    int* __restrict__ topk_pack, float* __restrict__ topk_w,
    int* __restrict__ blkcnt) {
  __shared__ float wgs[NE][DIM];
  __shared__ int hist[NE];
  const int tid = threadIdx.x;
  for (int d = tid; d < DIM; d += 256) {
#pragma unroll
    for (int e = 0; e < NE; e++) wgs[e][d] = Wg[d * NE + e];
  }
  if (tid < NE) hist[tid] = 0;
  __syncthreads();
  const int wave = tid >> 6, lane = tid & 63;
  for (int tk = wave; tk < 32; tk += 4) {
    const int t = blockIdx.x * 32 + tk;
    const float* xr = X + (size_t)t * DIM;
    {
      const float4* xp = (const float4*)(xr + lane * 16);
      float4 v0 = xp[0], v1 = xp[1], v2 = xp[2], v3 = xp[3];
      uint4 w0, w1;
      w0.x = f2bf(v0.x) | ((unsigned)f2bf(v0.y) << 16);
      w0.y = f2bf(v0.z) | ((unsigned)f2bf(v0.w) << 16);
      w0.z = f2bf(v1.x) | ((unsigned)f2bf(v1.y) << 16);
      w0.w = f2bf(v1.z) | ((unsigned)f2bf(v1.w) << 16);
      w1.x = f2bf(v2.x) | ((unsigned)f2bf(v2.y) << 16);
      w1.y = f2bf(v2.z) | ((unsigned)f2bf(v2.w) << 16);
      w1.z = f2bf(v3.x) | ((unsigned)f2bf(v3.y) << 16);
      w1.w = f2bf(v3.z) | ((unsigned)f2bf(v3.w) << 16);
      uint4* op2 = (uint4*)(Xb + (size_t)t * DIM + lane * 16);
      op2[0] = w0; op2[1] = w1;
    }
    float acc[NE];
#pragma unroll
    for (int e = 0; e < NE; e++) acc[e] = 0.f;
#pragma unroll
    for (int j = 0; j < 16; j++) {
      float xv = xr[lane + j * 64];
#pragma unroll
      for (int e = 0; e < NE; e++) acc[e] += xv * wgs[e][lane + j * 64];
    }
#pragma unroll
    for (int e = 0; e < NE; e++) {
#pragma unroll
      for (int off = 32; off > 0; off >>= 1) acc[e] += __shfl_xor(acc[e], off, 64);
    }
    if (lane == 0) {
      float p[NE];
      float mx = -1e30f;
#pragma unroll
      for (int e = 0; e < NE; e++) { p[e] = acc[e] + bg[e]; mx = fmaxf(mx, p[e]); }
      float sum = 0.f;
#pragma unroll
      for (int e = 0; e < NE; e++) { p[e] = expf(p[e] - mx); sum += p[e]; }
      float inv = 1.f / sum;
#pragma unroll
      for (int e = 0; e < NE; e++) p[e] *= inv;
      int i1 = 0; float v1 = p[0];
#pragma unroll
      for (int e = 1; e < NE; e++) if (p[e] >= v1) { v1 = p[e]; i1 = e; }
      int i2 = (i1 == 0) ? 1 : 0; float v2 = p[i2];
#pragma unroll
      for (int e = 0; e < NE; e++) {
        if (e == i1) continue;
        if (p[e] >= v2 && e != i2) { v2 = p[e]; i2 = e; }
      }
      topk_pack[t] = i1 | (i2 << 4);
      topk_w[t * 2 + 0] = v1; topk_w[t * 2 + 1] = v2;
      atomicAdd(&hist[i1], 1); atomicAdd(&hist[i2], 1);
    }
  }
  __syncthreads();
  if (tid < NE) blkcnt[blockIdx.x * NE + tid] = hist[tid];
}

// ------- scatter with integrated prefix; tp = BM=128 tile prefix -------
__global__ void scatter_kernel(const int* __restrict__ blkcnt,
                               const int* __restrict__ topk_pack,
                               int* __restrict__ counts, int* __restrict__ row_start,
                               int* __restrict__ tp, int* __restrict__ list) {
  __shared__ int lofs[NE];
  const int lane = threadIdx.x;   // 64
  const int myb = blockIdx.x;     // 128
  int s = 0, t = 0;
#pragma unroll
  for (int e = 0; e < NE; e++) {
    int c0 = blkcnt[lane * NE + e], c1 = blkcnt[(lane + 64) * NE + e];
    int tote = c0 + c1;
    int pre = (lane < myb ? c0 : 0) + (lane + 64 < myb ? c1 : 0);
#pragma unroll
    for (int off = 32; off > 0; off >>= 1) {
      tote += __shfl_xor(tote, off, 64);
      pre  += __shfl_xor(pre,  off, 64);
    }
    if (lane == 0) lofs[e] = s + pre;
    if (myb == 0 && lane == 0) { counts[e] = tote; row_start[e] = s; tp[e] = t; }
    s += tote; t += (tote + 127) >> 7;
  }
  if (myb == 0 && lane == 0) tp[NE] = t;
  __syncthreads();
  if (lane < 32) {
    int tok = myb * 32 + lane;
    int pk = topk_pack[tok];
    int e1 = pk & 15, e2 = (pk >> 4) & 15;
    int p1 = atomicAdd(&lofs[e1], 1); list[p1] = tok << 1;
    int p2 = atomicAdd(&lofs[e2], 1); list[p2] = (tok << 1) | 1;
  }
}

// ==== stage A: 128x128, BK=32, single-buffer, high-occupancy (6 waves/EU) ====
__global__ __launch_bounds__(256, 6) void ffn_a_kernel(
    const unsigned short* __restrict__ Xb,
    const unsigned short* __restrict__ W13t,
    const float* __restrict__ b1, const float* __restrict__ b3,
    const int* __restrict__ counts, const int* __restrict__ row_start,
    const int* __restrict__ tp, const int* __restrict__ list,
    unsigned short* __restrict__ h_buf) {
  __shared__ unsigned short As[128 * 32];   // 8KB
  __shared__ unsigned short Bs[128 * 32];   // 8KB
  const int by = blockIdx.y;
  if (by >= tp[NE]) return;
  int e = 0;
#pragma unroll
  for (int k = 1; k < NE; k++) if (by >= tp[k]) e = k;
  const int ne = counts[e], rs = row_start[e];
  const int m0 = (by - tp[e]) * 128;
  const int n0 = blockIdx.x * 128;           // interleaved col space [0,4096)

  const int tid = threadIdx.x;
  const int wave = tid >> 6, lane = tid & 63;
  const int lr = lane & 15, lk = lane >> 4;
  const int wm = (wave >> 1) * 64, wn = (wave & 1) * 64;

  // staging: instr (wave,i) covers rows (wave*2+i)*16 + (lane>>2), slot lane&3 (64B rows)
  // LDS slot q of row r holds global col16 (q ^ ((r>>1)&3)); (r>>1)&3 == (lane>>3)&3
  const int scs = ((lane & 3) ^ ((lane >> 3) & 3)) * 8;
  const unsigned short* asrc[2];
  const unsigned short* bsrc[2];
#pragma unroll
  for (int i = 0; i < 2; i++) {
    int sr = (wave * 2 + i) * 16 + (lane >> 2);
    int rr = m0 + sr; if (rr >= ne) rr = m0;
    int tok = list[rs + rr] >> 1;
    asrc[i] = Xb + (size_t)tok * DIM + scs;
    bsrc[i] = W13t + ((size_t)e * 2 * HID + n0 + sr) * DIM + scs;
  }

  f32x4 acc[4][4];
  const f32x4 zero = {0.f, 0.f, 0.f, 0.f};
#pragma unroll
  for (int m = 0; m < 4; m++)
#pragma unroll
    for (int n = 0; n < 4; n++) acc[m][n] = zero;

  const int sl = (lk ^ ((lr >> 1) & 3)) * 8;   // swizzled read slot (shorts)

  for (int k0 = 0; k0 < DIM; k0 += 32) {
#pragma unroll
    for (int i = 0; i < 2; i++) {
      gload16(asrc[i] + k0, &As[(wave * 2 + i) * 512]);
      gload16(bsrc[i] + k0, &Bs[(wave * 2 + i) * 512]);
    }
    __syncthreads();
    bf16x8 a[4], b[4];
#pragma unroll
    for (int m = 0; m < 4; m++)
      a[m] = *(const bf16x8*)&As[(wm + m * 16 + lr) * 32 + sl];
#pragma unroll
    for (int n = 0; n < 4; n++)
      b[n] = *(const bf16x8*)&Bs[(wn + n * 16 + lr) * 32 + sl];
#pragma unroll
    for (int m = 0; m < 4; m++)
#pragma unroll
      for (int n = 0; n < 4; n++)
        acc[m][n] = __builtin_amdgcn_mfma_f32_16x16x32_bf16(a[m], b[n], acc[m][n], 0, 0, 0);
    __syncthreads();
  }

  // SwiGLU epilogue: frag pair (2g,2g+1) = (h1,h3); h = ((n0+wn)>>5 + g)*16 + lr
  const int hq = (n0 + wn) >> 5;
#pragma unroll
  for (int g = 0; g < 2; g++) {
    int h = (hq + g) * 16 + lr;
    float b1v = b1[e * HID + h];
    float b3v = b3[e * HID + h];
#pragma unroll
    for (int m = 0; m < 4; m++) {
#pragma unroll
      for (int j = 0; j < 4; j++) {
        int rr = m0 + wm + m * 16 + lk * 4 + j;
        if (rr < ne) {
          float h1 = acc[m][2 * g][j] + b1v;
          float h3 = acc[m][2 * g + 1][j] + b3v;
          float v = h1 * h3;
          h_buf[(size_t)(rs + rr) * HID + h] = f2bf(v / (1.f + expf(-v)));
        }
      }
    }
  }
}

// ==== stage B: 128x128, BK=32, single-buffer, high-occupancy, bf16 out ====
__global__ __launch_bounds__(256, 6) void ffn_b_kernel(
    const unsigned short* __restrict__ h_buf,
    const unsigned short* __restrict__ W2t,
    const float* __restrict__ b2,
    const int* __restrict__ counts, const int* __restrict__ row_start,
    const int* __restrict__ tp, const int* __restrict__ list,
    const float* __restrict__ topk_w, unsigned short* __restrict__ ob) {
  __shared__ unsigned short As[128 * 32];
  __shared__ unsigned short Bs[128 * 32];
  const int by = blockIdx.y;
  if (by >= tp[NE]) return;
  int e = 0;
#pragma unroll
  for (int k = 1; k < NE; k++) if (by >= tp[k]) e = k;
  const int ne = counts[e], rs = row_start[e];
  const int m0 = (by - tp[e]) * 128;
  const int n0 = blockIdx.x * 128;

  const int tid = threadIdx.x;
  const int wave = tid >> 6, lane = tid & 63;
  const int lr = lane & 15, lk = lane >> 4;
  const int wm = (wave >> 1) * 64, wn = (wave & 1) * 64;

  const int scs = ((lane & 3) ^ ((lane >> 3) & 3)) * 8;
  const unsigned short* asrc[2];
  const unsigned short* bsrc[2];
#pragma unroll
  for (int i = 0; i < 2; i++) {
    int sr = (wave * 2 + i) * 16 + (lane >> 2);
    asrc[i] = h_buf + (size_t)(rs + m0 + sr) * HID + scs;   // padded rows, in-bounds
    bsrc[i] = W2t + ((size_t)e * OUTD + n0 + sr) * HID + scs;
  }

  f32x4 acc[4][4];
  const f32x4 zero = {0.f, 0.f, 0.f, 0.f};
#pragma unroll
  for (int m = 0; m < 4; m++)
#pragma unroll
    for (int n = 0; n < 4; n++) acc[m][n] = zero;

  const int sl = (lk ^ ((lr >> 1) & 3)) * 8;

  for (int k0 = 0; k0 < HID; k0 += 32) {
#pragma unroll
    for (int i = 0; i < 2; i++) {
      gload16(asrc[i] + k0, &As[(wave * 2 + i) * 512]);
      gload16(bsrc[i] + k0, &Bs[(wave * 2 + i) * 512]);
    }
    __syncthreads();
    bf16x8 a[4], b[4];
#pragma unroll
    for (int m = 0; m < 4; m++)
      a[m] = *(const bf16x8*)&As[(wm + m * 16 + lr) * 32 + sl];
#pragma unroll
    for (int n = 0; n < 4; n++)
      b[n] = *(const bf16x8*)&Bs[(wn + n * 16 + lr) * 32 + sl];
#pragma unroll
    for (int m = 0; m < 4; m++)
#pragma unroll
      for (int n = 0; n < 4; n++)
        acc[m][n] = __builtin_amdgcn_mfma_f32_16x16x32_bf16(a[m], b[n], acc[m][n], 0, 0, 0);
    __syncthreads();
  }

#pragma unroll
  for (int n = 0; n < 4; n++) {
    int col = n0 + wn + n * 16 + lr;
    float b2v = b2[e * OUTD + col];
#pragma unroll
    for (int m = 0; m < 4; m++) {
#pragma unroll
      for (int j = 0; j < 4; j++) {
        int rr = m0 + wm + m * 16 + lk * 4 + j;
        if (rr < ne) {
          int entry = list[rs + rr];
          float w = topk_w[entry];
          ob[(size_t)entry * OUTD + col] = f2bf(w * (acc[m][n][j] + b2v));
        }
      }
    }
  }
}

// ---------------- final: out = (ob0 + ob1) @ Wf + bf ; XCD-grouped m-bands ----------------
__global__ __launch_bounds__(256) void final_kernel(
    const unsigned short* __restrict__ ob, const unsigned short* __restrict__ Wft,
    const float* __restrict__ bfv, float* __restrict__ out) {
  const int bid = blockIdx.x;
  const int n0 = (bid >> 5) * 128;
  const int m0 = ((bid & 7) + 8 * ((bid >> 3) & 3)) * 128;

  __shared__ unsigned short As[128 * 64];
  __shared__ unsigned short Bs[128 * 64];

  const int tid = threadIdx.x;
  const int wave = tid >> 6, lane = tid & 63;
  const int lrow = lane >> 3;
  const int lcol = (lane & 7) * 8;

  const unsigned short* bsrc[4];
#pragma unroll
  for (int i = 0; i < 4; i++) {
    int sr = (wave * 4 + i) * 8 + lrow;
    bsrc[i] = Wft + (size_t)(n0 + sr) * DIM + lcol;
  }

  const int wm = (wave >> 1) * 64, wn = (wave & 1) * 64;
  const int lr = lane & 15, lk = lane >> 4;

  f32x4 acc[4][4];
  const f32x4 zero = {0.f, 0.f, 0.f, 0.f};
#pragma unroll
  for (int m = 0; m < 4; m++)
#pragma unroll
    for (int n = 0; n < 4; n++) acc[m][n] = zero;

  for (int k0 = 0; k0 < DIM; k0 += 64) {
#pragma unroll
    for (int g = 0; g < 8; g++) {
      int idx = g * 256 + tid;
      int r = idx >> 4;
      int c4 = (idx & 15) * 4;
      ushort4 a0 = *(const ushort4*)&ob[((size_t)(m0 + r) * 2) * OUTD + k0 + c4];
      ushort4 a1 = *(const ushort4*)&ob[((size_t)(m0 + r) * 2 + 1) * OUTD + k0 + c4];
      ushort4 u;
      u.x = f2bf(b2f(a0.x) + b2f(a1.x)); u.y = f2bf(b2f(a0.y) + b2f(a1.y));
      u.z = f2bf(b2f(a0.z) + b2f(a1.z)); u.w = f2bf(b2f(a0.w) + b2f(a1.w));
      *(ushort4*)&As[r * 64 + c4] = u;
    }
#pragma unroll
    for (int i = 0; i < 4; i++) gload16(bsrc[i] + k0, &Bs[(wave * 4 + i) * 512]);
    __syncthreads();
#pragma unroll
    for (int kk = 0; kk < 2; kk++) {
      bf16x8 a[4], b[4];
#pragma unroll
      for (int m = 0; m < 4; m++)
        a[m] = *(const bf16x8*)&As[(wm + m * 16 + lr) * 64 + kk * 32 + lk * 8];
#pragma unroll
      for (int n = 0; n < 4; n++)
        b[n] = *(const bf16x8*)&Bs[(wn + n * 16 + lr) * 64 + kk * 32 + lk * 8];
#pragma unroll
      for (int m = 0; m < 4; m++)
#pragma unroll
        for (int n = 0; n < 4; n++)
          acc[m][n] = __builtin_amdgcn_mfma_f32_16x16x32_bf16(a[m], b[n], acc[m][n], 0, 0, 0);
    }
    __syncthreads();
  }

#pragma unroll
  for (int n = 0; n < 4; n++) {
    int col = n0 + wn + n * 16 + lr;
    float bv = bfv[col];
#pragma unroll
    for (int m = 0; m < 4; m++) {
#pragma unroll
      for (int j = 0; j < 4; j++) {
        int r = m0 + wm + m * 16 + lk * 4 + j;
        out[(size_t)r * OUTD + col] = acc[m][n][j] + bv;
      }
    }
  }
}

extern "C" void kernel_launch(void* const* d_in, const int* in_sizes, int n_in,
                              void* d_out, int out_size, void* d_ws, size_t ws_size,
                              hipStream_t stream) {
  const float* X   = (const float*)d_in[0];
  const float* W1  = (const float*)d_in[1];
  const float* b1  = (const float*)d_in[2];
  const float* W3  = (const float*)d_in[3];
  const float* b3  = (const float*)d_in[4];
  const float* W2  = (const float*)d_in[5];
  const float* b2  = (const float*)d_in[6];
  const float* Wg  = (const float*)d_in[7];
  const float* bg  = (const float*)d_in[8];
  const float* Wf  = (const float*)d_in[9];
  const float* bfv = (const float*)d_in[10];
  float* out = (float*)d_out;

  char* p = (char*)d_ws;
  auto alloc = [&](size_t bytes) { char* r = p; p += (bytes + 255) & ~(size_t)255; return r; };
  unsigned short* Xb   = (unsigned short*)alloc((size_t)NTOK * DIM * 2);
  unsigned short* W13t = (unsigned short*)alloc((size_t)NE * 2 * HID * DIM * 2);
  unsigned short* W2t  = (unsigned short*)alloc((size_t)NE * OUTD * HID * 2);
  unsigned short* Wft  = (unsigned short*)alloc((size_t)OUTD * DIM * 2);
  unsigned short* hbuf = (unsigned short*)alloc((size_t)(NTOK * 2 + 256) * HID * 2);
  unsigned short* ob   = (unsigned short*)alloc((size_t)NTOK * 2 * OUTD * 2);
  int* topk_pack       = (int*)alloc(NTOK * 4);
  float* topk_w        = (float*)alloc(NTOK * 2 * 4);
  int* counts          = (int*)alloc(NE * 4);
  int* row_start       = (int*)alloc(NE * 4);
  int* tp              = (int*)alloc((NE + 1) * 4);
  int* blkcnt          = (int*)alloc(128 * NE * 4);
  int* list            = (int*)alloc(NTOK * 2 * 4);

  gating_kernel<<<128, 256, 0, stream>>>(X, Wg, bg, Xb, topk_pack, topk_w, blkcnt);
  tcast_all_kernel<<<50176, 256, 0, stream>>>(W1, W3, W2, Wf, W13t, W2t, Wft);

  scatter_kernel<<<128, 64, 0, stream>>>(blkcnt, topk_pack, counts, row_start, tp, list);

  // ffn_a: 128x128 tiles over interleaved N=4096 -> grid 32 x 72
  ffn_a_kernel<<<dim3(2 * HID / 128, 72), 256, 0, stream>>>(
      Xb, W13t, b1, b3, counts, row_start, tp, list, hbuf);
  // ffn_b: 128x128 tiles
  ffn_b_kernel<<<dim3(OUTD / 128, 72), 256, 0, stream>>>(
      hbuf, W2t, b2, counts, row_start, tp, list, topk_w, ob);
  final_kernel<<<256, 256, 0, stream>>>(ob, Wft, bfv, out);
}

// Round 12
// 302.627 us; speedup vs baseline: 3.3491x; 3.3491x over previous
//
#include <hip/hip_runtime.h>

#define DIM  1024
#define HID  2048
#define OUTD 1024
#define NE   8
#define NTOK 4096

using bf16x8 = __attribute__((ext_vector_type(8))) short;
using f32x4  = __attribute__((ext_vector_type(4))) float;

__device__ __forceinline__ unsigned short f2bf(float f) {
  unsigned int u = __builtin_bit_cast(unsigned int, f);
  u += 0x7fff + ((u >> 16) & 1);   // round-to-nearest-even
  return (unsigned short)(u >> 16);
}
__device__ __forceinline__ float b2f(unsigned short u) {
  unsigned int v = (unsigned int)u << 16;
  return __builtin_bit_cast(float, v);
}

__device__ __forceinline__ void gload16(const void* g, void* l) {
  __builtin_amdgcn_global_load_lds(
      (const __attribute__((address_space(1))) void*)g,
      (__attribute__((address_space(3))) void*)l, 16, 0, 0);
}

// ---- shared 32x32 transpose-cast tile body ----
__device__ __forceinline__ void tc_tile(const float* __restrict__ inp, int C,
                                        unsigned short* __restrict__ op, int R,
                                        int c0, int r0, float (*tile)[33],
                                        int interleave, int s) {
  int tx = threadIdx.x & 31, ty = threadIdx.x >> 5;
#pragma unroll
  for (int j = 0; j < 4; j++)
    tile[ty + j * 8][tx] = inp[(size_t)(r0 + ty + j * 8) * C + c0 + tx];
  __syncthreads();
  int c = threadIdx.x >> 3, q = threadIdx.x & 7;
  int h = c0 + c;
  int orow = interleave ? (32 * (h >> 4) + 16 * s + (h & 15)) : h;
  ushort4 u;
  u.x = f2bf(tile[q * 4 + 0][c]); u.y = f2bf(tile[q * 4 + 1][c]);
  u.z = f2bf(tile[q * 4 + 2][c]); u.w = f2bf(tile[q * 4 + 3][c]);
  *(ushort4*)&op[(size_t)orow * R + r0 + q * 4] = u;
}

// ---- merged weight transposes: one launch ----
__global__ void tcast_all_kernel(const float* __restrict__ W1, const float* __restrict__ W3,
                                 const float* __restrict__ W2, const float* __restrict__ Wf,
                                 unsigned short* __restrict__ W13t,
                                 unsigned short* __restrict__ W2t,
                                 unsigned short* __restrict__ Wft) {
  __shared__ float tile[32][33];
  int b = blockIdx.x;
  if (b < 32768) {
    int z = b >> 11, rem = b & 2047;
    int e = z & 7, s = z >> 3;
    tc_tile((s ? W3 : W1) + (size_t)e * DIM * HID, HID,
            W13t + (size_t)e * 2 * HID * DIM, DIM,
            (rem & 63) * 32, (rem >> 6) * 32, tile, 1, s);
  } else if (b < 49152) {
    int i = b - 32768;
    int z = i >> 11, rem = i & 2047;
    tc_tile(W2 + (size_t)z * HID * OUTD, OUTD, W2t + (size_t)z * OUTD * HID, HID,
            (rem & 31) * 32, (rem >> 5) * 32, tile, 0, 0);
  } else {
    int i = b - 49152;
    tc_tile(Wf, OUTD, Wft, DIM, (i & 31) * 32, (i >> 5) * 32, tile, 0, 0);
  }
}

// ---------------- gating + fused X cast + per-block histogram ----------------
__global__ __launch_bounds__(256) void gating_kernel(
    const float* __restrict__ X, const float* __restrict__ Wg,
    const float* __restrict__ bg, unsigned short* __restrict__ Xb,
    int* __restrict__ topk_pack, float* __restrict__ topk_w,
    int* __restrict__ blkcnt) {
  __shared__ float wgs[NE][DIM];
  __shared__ int hist[NE];
  const int tid = threadIdx.x;
  for (int d = tid; d < DIM; d += 256) {
#pragma unroll
    for (int e = 0; e < NE; e++) wgs[e][d] = Wg[d * NE + e];
  }
  if (tid < NE) hist[tid] = 0;
  __syncthreads();
  const int wave = tid >> 6, lane = tid & 63;
  for (int tk = wave; tk < 32; tk += 4) {
    const int t = blockIdx.x * 32 + tk;
    const float* xr = X + (size_t)t * DIM;
    {
      const float4* xp = (const float4*)(xr + lane * 16);
      float4 v0 = xp[0], v1 = xp[1], v2 = xp[2], v3 = xp[3];
      uint4 w0, w1;
      w0.x = f2bf(v0.x) | ((unsigned)f2bf(v0.y) << 16);
      w0.y = f2bf(v0.z) | ((unsigned)f2bf(v0.w) << 16);
      w0.z = f2bf(v1.x) | ((unsigned)f2bf(v1.y) << 16);
      w0.w = f2bf(v1.z) | ((unsigned)f2bf(v1.w) << 16);
      w1.x = f2bf(v2.x) | ((unsigned)f2bf(v2.y) << 16);
      w1.y = f2bf(v2.z) | ((unsigned)f2bf(v2.w) << 16);
      w1.z = f2bf(v3.x) | ((unsigned)f2bf(v3.y) << 16);
      w1.w = f2bf(v3.z) | ((unsigned)f2bf(v3.w) << 16);
      uint4* op2 = (uint4*)(Xb + (size_t)t * DIM + lane * 16);
      op2[0] = w0; op2[1] = w1;
    }
    float acc[NE];
#pragma unroll
    for (int e = 0; e < NE; e++) acc[e] = 0.f;
#pragma unroll
    for (int j = 0; j < 16; j++) {
      float xv = xr[lane + j * 64];
#pragma unroll
      for (int e = 0; e < NE; e++) acc[e] += xv * wgs[e][lane + j * 64];
    }
#pragma unroll
    for (int e = 0; e < NE; e++) {
#pragma unroll
      for (int off = 32; off > 0; off >>= 1) acc[e] += __shfl_xor(acc[e], off, 64);
    }
    if (lane == 0) {
      float p[NE];
      float mx = -1e30f;
#pragma unroll
      for (int e = 0; e < NE; e++) { p[e] = acc[e] + bg[e]; mx = fmaxf(mx, p[e]); }
      float sum = 0.f;
#pragma unroll
      for (int e = 0; e < NE; e++) { p[e] = expf(p[e] - mx); sum += p[e]; }
      float inv = 1.f / sum;
#pragma unroll
      for (int e = 0; e < NE; e++) p[e] *= inv;
      int i1 = 0; float v1 = p[0];
#pragma unroll
      for (int e = 1; e < NE; e++) if (p[e] >= v1) { v1 = p[e]; i1 = e; }
      int i2 = (i1 == 0) ? 1 : 0; float v2 = p[i2];
#pragma unroll
      for (int e = 0; e < NE; e++) {
        if (e == i1) continue;
        if (p[e] >= v2 && e != i2) { v2 = p[e]; i2 = e; }
      }
      topk_pack[t] = i1 | (i2 << 4);
      topk_w[t * 2 + 0] = v1; topk_w[t * 2 + 1] = v2;
      atomicAdd(&hist[i1], 1); atomicAdd(&hist[i2], 1);
    }
  }
  __syncthreads();
  if (tid < NE) blkcnt[blockIdx.x * NE + tid] = hist[tid];
}

// ------- scatter with integrated prefix; tp = BM=128 tile prefix -------
__global__ void scatter_kernel(const int* __restrict__ blkcnt,
                               const int* __restrict__ topk_pack,
                               int* __restrict__ counts, int* __restrict__ row_start,
                               int* __restrict__ tp, int* __restrict__ list) {
  __shared__ int lofs[NE];
  const int lane = threadIdx.x;   // 64
  const int myb = blockIdx.x;     // 128
  int s = 0, t = 0;
#pragma unroll
  for (int e = 0; e < NE; e++) {
    int c0 = blkcnt[lane * NE + e], c1 = blkcnt[(lane + 64) * NE + e];
    int tote = c0 + c1;
    int pre = (lane < myb ? c0 : 0) + (lane + 64 < myb ? c1 : 0);
#pragma unroll
    for (int off = 32; off > 0; off >>= 1) {
      tote += __shfl_xor(tote, off, 64);
      pre  += __shfl_xor(pre,  off, 64);
    }
    if (lane == 0) lofs[e] = s + pre;
    if (myb == 0 && lane == 0) { counts[e] = tote; row_start[e] = s; tp[e] = t; }
    s += tote; t += (tote + 127) >> 7;
  }
  if (myb == 0 && lane == 0) tp[NE] = t;
  __syncthreads();
  if (lane < 32) {
    int tok = myb * 32 + lane;
    int pk = topk_pack[tok];
    int e1 = pk & 15, e2 = (pk >> 4) & 15;
    int p1 = atomicAdd(&lofs[e1], 1); list[p1] = tok << 1;
    int p2 = atomicAdd(&lofs[e2], 1); list[p2] = (tok << 1) | 1;
  }
}

// ============ stage A: 128x128, BK=64, m97 single-buffer (R6-proven) ============
__global__ __launch_bounds__(256, 3) void ffn_a_kernel(
    const unsigned short* __restrict__ Xb,
    const unsigned short* __restrict__ W13t,
    const float* __restrict__ b1, const float* __restrict__ b3,
    const int* __restrict__ counts, const int* __restrict__ row_start,
    const int* __restrict__ tp, const int* __restrict__ list,
    unsigned short* __restrict__ h_buf) {
  __shared__ unsigned short As[128 * 64];
  __shared__ unsigned short Bs[128 * 64];
  const int by = blockIdx.y;
  if (by >= tp[NE]) return;
  int e = 0;
#pragma unroll
  for (int k = 1; k < NE; k++) if (by >= tp[k]) e = k;
  const int ne = counts[e], rs = row_start[e];
  const int m0 = (by - tp[e]) * 128;
  const int n0 = blockIdx.x * 128;           // interleaved col space [0,4096)

  const int tid = threadIdx.x;
  const int wave = tid >> 6, lane = tid & 63;
  const int lr = lane & 15, lk = lane >> 4;
  const int wm = (wave >> 1) * 64, wn = (wave & 1) * 64;

  // staging rows (wave*4+i)*8 + (lane>>3), slot lane&7 (128B rows)
  // LDS slot q of row r holds global col16 (q ^ (r&7))   [conflict-free, R6-proven]
  const int scs = ((lane & 7) ^ (lane >> 3)) * 8;
  const unsigned short* asrc[4];
  const unsigned short* bsrc[4];
#pragma unroll
  for (int i = 0; i < 4; i++) {
    int sr = (wave * 4 + i) * 8 + (lane >> 3);
    int rr = m0 + sr; if (rr >= ne) rr = m0;
    int tok = list[rs + rr] >> 1;
    asrc[i] = Xb + (size_t)tok * DIM + scs;
    bsrc[i] = W13t + ((size_t)e * 2 * HID + n0 + sr) * DIM + scs;
  }

  f32x4 acc[4][4];
  const f32x4 zero = {0.f, 0.f, 0.f, 0.f};
#pragma unroll
  for (int m = 0; m < 4; m++)
#pragma unroll
    for (int n = 0; n < 4; n++) acc[m][n] = zero;

  const int sx = lr & 7;

  for (int k0 = 0; k0 < DIM; k0 += 64) {
#pragma unroll
    for (int i = 0; i < 4; i++) {
      gload16(asrc[i] + k0, &As[(wave * 4 + i) * 512]);
      gload16(bsrc[i] + k0, &Bs[(wave * 4 + i) * 512]);
    }
    __syncthreads();
#pragma unroll
    for (int kk = 0; kk < 2; kk++) {
      const int sl = ((kk * 4 + lk) ^ sx) * 8;
      bf16x8 a[4], b[4];
#pragma unroll
      for (int m = 0; m < 4; m++)
        a[m] = *(const bf16x8*)&As[(wm + m * 16 + lr) * 64 + sl];
#pragma unroll
      for (int n = 0; n < 4; n++)
        b[n] = *(const bf16x8*)&Bs[(wn + n * 16 + lr) * 64 + sl];
#pragma unroll
      for (int m = 0; m < 4; m++)
#pragma unroll
        for (int n = 0; n < 4; n++)
          acc[m][n] = __builtin_amdgcn_mfma_f32_16x16x32_bf16(a[m], b[n], acc[m][n], 0, 0, 0);
    }
    __syncthreads();
  }

  // SwiGLU epilogue: frag pair (2g,2g+1) = (h1,h3); h = ((n0+wn)>>5 + g)*16 + lr
  const int hq = (n0 + wn) >> 5;
#pragma unroll
  for (int g = 0; g < 2; g++) {
    int h = (hq + g) * 16 + lr;
    float b1v = b1[e * HID + h];
    float b3v = b3[e * HID + h];
#pragma unroll
    for (int m = 0; m < 4; m++) {
#pragma unroll
      for (int j = 0; j < 4; j++) {
        int rr = m0 + wm + m * 16 + lk * 4 + j;
        if (rr < ne) {
          float h1 = acc[m][2 * g][j] + b1v;
          float h3 = acc[m][2 * g + 1][j] + b3v;
          float v = h1 * h3;
          h_buf[(size_t)(rs + rr) * HID + h] = f2bf(v / (1.f + expf(-v)));
        }
      }
    }
  }
}

// ============ stage B: 128x128, BK=64, m97 single-buffer, bf16 out (R9-proven) ============
__global__ __launch_bounds__(256, 3) void ffn_b_kernel(
    const unsigned short* __restrict__ h_buf,
    const unsigned short* __restrict__ W2t,
    const float* __restrict__ b2,
    const int* __restrict__ counts, const int* __restrict__ row_start,
    const int* __restrict__ tp, const int* __restrict__ list,
    const float* __restrict__ topk_w, unsigned short* __restrict__ ob) {
  __shared__ unsigned short As[128 * 64];
  __shared__ unsigned short Bs[128 * 64];
  const int by = blockIdx.y;
  if (by >= tp[NE]) return;
  int e = 0;
#pragma unroll
  for (int k = 1; k < NE; k++) if (by >= tp[k]) e = k;
  const int ne = counts[e], rs = row_start[e];
  const int m0 = (by - tp[e]) * 128;
  const int n0 = blockIdx.x * 128;

  const int tid = threadIdx.x;
  const int wave = tid >> 6, lane = tid & 63;
  const int lr = lane & 15, lk = lane >> 4;
  const int wm = (wave >> 1) * 64, wn = (wave & 1) * 64;

  const int scs = ((lane & 7) ^ (lane >> 3)) * 8;
  const unsigned short* asrc[4];
  const unsigned short* bsrc[4];
#pragma unroll
  for (int i = 0; i < 4; i++) {
    int sr = (wave * 4 + i) * 8 + (lane >> 3);
    asrc[i] = h_buf + (size_t)(rs + m0 + sr) * HID + scs;   // padded rows, in-bounds
    bsrc[i] = W2t + ((size_t)e * OUTD + n0 + sr) * HID + scs;
  }

  f32x4 acc[4][4];
  const f32x4 zero = {0.f, 0.f, 0.f, 0.f};
#pragma unroll
  for (int m = 0; m < 4; m++)
#pragma unroll
    for (int n = 0; n < 4; n++) acc[m][n] = zero;

  const int sx = lr & 7;

  for (int k0 = 0; k0 < HID; k0 += 64) {
#pragma unroll
    for (int i = 0; i < 4; i++) {
      gload16(asrc[i] + k0, &As[(wave * 4 + i) * 512]);
      gload16(bsrc[i] + k0, &Bs[(wave * 4 + i) * 512]);
    }
    __syncthreads();
#pragma unroll
    for (int kk = 0; kk < 2; kk++) {
      const int sl = ((kk * 4 + lk) ^ sx) * 8;
      bf16x8 a[4], b[4];
#pragma unroll
      for (int m = 0; m < 4; m++)
        a[m] = *(const bf16x8*)&As[(wm + m * 16 + lr) * 64 + sl];
#pragma unroll
      for (int n = 0; n < 4; n++)
        b[n] = *(const bf16x8*)&Bs[(wn + n * 16 + lr) * 64 + sl];
#pragma unroll
      for (int m = 0; m < 4; m++)
#pragma unroll
        for (int n = 0; n < 4; n++)
          acc[m][n] = __builtin_amdgcn_mfma_f32_16x16x32_bf16(a[m], b[n], acc[m][n], 0, 0, 0);
    }
    __syncthreads();
  }

#pragma unroll
  for (int n = 0; n < 4; n++) {
    int col = n0 + wn + n * 16 + lr;
    float b2v = b2[e * OUTD + col];
#pragma unroll
    for (int m = 0; m < 4; m++) {
#pragma unroll
      for (int j = 0; j < 4; j++) {
        int rr = m0 + wm + m * 16 + lk * 4 + j;
        if (rr < ne) {
          int entry = list[rs + rr];
          float w = topk_w[entry];
          ob[(size_t)entry * OUTD + col] = f2bf(w * (acc[m][n][j] + b2v));
        }
      }
    }
  }
}

// ---------------- final: out = (ob0 + ob1) @ Wf + bf ; XCD-grouped m-bands ----------------
__global__ __launch_bounds__(256) void final_kernel(
    const unsigned short* __restrict__ ob, const unsigned short* __restrict__ Wft,
    const float* __restrict__ bfv, float* __restrict__ out) {
  const int bid = blockIdx.x;
  const int n0 = (bid >> 5) * 128;
  const int m0 = ((bid & 7) + 8 * ((bid >> 3) & 3)) * 128;

  __shared__ unsigned short As[128 * 64];
  __shared__ unsigned short Bs[128 * 64];

  const int tid = threadIdx.x;
  const int wave = tid >> 6, lane = tid & 63;
  const int lrow = lane >> 3;
  const int lcol = (lane & 7) * 8;

  const unsigned short* bsrc[4];
#pragma unroll
  for (int i = 0; i < 4; i++) {
    int sr = (wave * 4 + i) * 8 + lrow;
    bsrc[i] = Wft + (size_t)(n0 + sr) * DIM + lcol;
  }

  const int wm = (wave >> 1) * 64, wn = (wave & 1) * 64;
  const int lr = lane & 15, lk = lane >> 4;

  f32x4 acc[4][4];
  const f32x4 zero = {0.f, 0.f, 0.f, 0.f};
#pragma unroll
  for (int m = 0; m < 4; m++)
#pragma unroll
    for (int n = 0; n < 4; n++) acc[m][n] = zero;

  for (int k0 = 0; k0 < DIM; k0 += 64) {
#pragma unroll
    for (int g = 0; g < 8; g++) {
      int idx = g * 256 + tid;
      int r = idx >> 4;
      int c4 = (idx & 15) * 4;
      ushort4 a0 = *(const ushort4*)&ob[((size_t)(m0 + r) * 2) * OUTD + k0 + c4];
      ushort4 a1 = *(const ushort4*)&ob[((size_t)(m0 + r) * 2 + 1) * OUTD + k0 + c4];
      ushort4 u;
      u.x = f2bf(b2f(a0.x) + b2f(a1.x)); u.y = f2bf(b2f(a0.y) + b2f(a1.y));
      u.z = f2bf(b2f(a0.z) + b2f(a1.z)); u.w = f2bf(b2f(a0.w) + b2f(a1.w));
      *(ushort4*)&As[r * 64 + c4] = u;
    }
#pragma unroll
    for (int i = 0; i < 4; i++) gload16(bsrc[i] + k0, &Bs[(wave * 4 + i) * 512]);
    __syncthreads();
#pragma unroll
    for (int kk = 0; kk < 2; kk++) {
      bf16x8 a[4], b[4];
#pragma unroll
      for (int m = 0; m < 4; m++)
        a[m] = *(const bf16x8*)&As[(wm + m * 16 + lr) * 64 + kk * 32 + lk * 8];
#pragma unroll
      for (int n = 0; n < 4; n++)
        b[n] = *(const bf16x8*)&Bs[(wn + n * 16 + lr) * 64 + kk * 32 + lk * 8];
#pragma unroll
      for (int m = 0; m < 4; m++)
#pragma unroll
        for (int n = 0; n < 4; n++)
          acc[m][n] = __builtin_amdgcn_mfma_f32_16x16x32_bf16(a[m], b[n], acc[m][n], 0, 0, 0);
    }
    __syncthreads();
  }

#pragma unroll
  for (int n = 0; n < 4; n++) {
    int col = n0 + wn + n * 16 + lr;
    float bv = bfv[col];
#pragma unroll
    for (int m = 0; m < 4; m++) {
#pragma unroll
      for (int j = 0; j < 4; j++) {
        int r = m0 + wm + m * 16 + lk * 4 + j;
        out[(size_t)r * OUTD + col] = acc[m][n][j] + bv;
      }
    }
  }
}

extern "C" void kernel_launch(void* const* d_in, const int* in_sizes, int n_in,
                              void* d_out, int out_size, void* d_ws, size_t ws_size,
                              hipStream_t stream) {
  const float* X   = (const float*)d_in[0];
  const float* W1  = (const float*)d_in[1];
  const float* b1  = (const float*)d_in[2];
  const float* W3  = (const float*)d_in[3];
  const float* b3  = (const float*)d_in[4];
  const float* W2  = (const float*)d_in[5];
  const float* b2  = (const float*)d_in[6];
  const float* Wg  = (const float*)d_in[7];
  const float* bg  = (const float*)d_in[8];
  const float* Wf  = (const float*)d_in[9];
  const float* bfv = (const float*)d_in[10];
  float* out = (float*)d_out;

  char* p = (char*)d_ws;
  auto alloc = [&](size_t bytes) { char* r = p; p += (bytes + 255) & ~(size_t)255; return r; };
  unsigned short* Xb   = (unsigned short*)alloc((size_t)NTOK * DIM * 2);
  unsigned short* W13t = (unsigned short*)alloc((size_t)NE * 2 * HID * DIM * 2);
  unsigned short* W2t  = (unsigned short*)alloc((size_t)NE * OUTD * HID * 2);
  unsigned short* Wft  = (unsigned short*)alloc((size_t)OUTD * DIM * 2);
  unsigned short* hbuf = (unsigned short*)alloc((size_t)(NTOK * 2 + 256) * HID * 2);
  unsigned short* ob   = (unsigned short*)alloc((size_t)NTOK * 2 * OUTD * 2);
  int* topk_pack       = (int*)alloc(NTOK * 4);
  float* topk_w        = (float*)alloc(NTOK * 2 * 4);
  int* counts          = (int*)alloc(NE * 4);
  int* row_start       = (int*)alloc(NE * 4);
  int* tp              = (int*)alloc((NE + 1) * 4);
  int* blkcnt          = (int*)alloc(128 * NE * 4);
  int* list            = (int*)alloc(NTOK * 2 * 4);

  gating_kernel<<<128, 256, 0, stream>>>(X, Wg, bg, Xb, topk_pack, topk_w, blkcnt);
  tcast_all_kernel<<<50176, 256, 0, stream>>>(W1, W3, W2, Wf, W13t, W2t, Wft);

  scatter_kernel<<<128, 64, 0, stream>>>(blkcnt, topk_pack, counts, row_start, tp, list);

  // ffn_a: 128x128 tiles over interleaved N=4096 -> grid 32 x 72
  ffn_a_kernel<<<dim3(2 * HID / 128, 72), 256, 0, stream>>>(
      Xb, W13t, b1, b3, counts, row_start, tp, list, hbuf);
  // ffn_b: 128x128 tiles
  ffn_b_kernel<<<dim3(OUTD / 128, 72), 256, 0, stream>>>(
      hbuf, W2t, b2, counts, row_start, tp, list, topk_w, ob);
  final_kernel<<<256, 256, 0, stream>>>(ob, Wft, bfv, out);
}

// Round 13
// 281.244 us; speedup vs baseline: 3.6037x; 1.0760x over previous
//
#include <hip/hip_runtime.h>

#define DIM  1024
#define HID  2048
#define OUTD 1024
#define NE   8
#define NTOK 4096

using bf16x8 = __attribute__((ext_vector_type(8))) short;
using f32x4  = __attribute__((ext_vector_type(4))) float;

__device__ __forceinline__ unsigned short f2bf(float f) {
  unsigned int u = __builtin_bit_cast(unsigned int, f);
  u += 0x7fff + ((u >> 16) & 1);   // round-to-nearest-even
  return (unsigned short)(u >> 16);
}
__device__ __forceinline__ float b2f(unsigned short u) {
  unsigned int v = (unsigned int)u << 16;
  return __builtin_bit_cast(float, v);
}

__device__ __forceinline__ void gload16(const void* g, void* l) {
  __builtin_amdgcn_global_load_lds(
      (const __attribute__((address_space(1))) void*)g,
      (__attribute__((address_space(3))) void*)l, 16, 0, 0);
}

// ---- shared 32x32 transpose-cast tile body ----
__device__ __forceinline__ void tc_tile(const float* __restrict__ inp, int C,
                                        unsigned short* __restrict__ op, int R,
                                        int c0, int r0, float (*tile)[33],
                                        int interleave, int s) {
  int tx = threadIdx.x & 31, ty = threadIdx.x >> 5;
#pragma unroll
  for (int j = 0; j < 4; j++)
    tile[ty + j * 8][tx] = inp[(size_t)(r0 + ty + j * 8) * C + c0 + tx];
  __syncthreads();
  int c = threadIdx.x >> 3, q = threadIdx.x & 7;
  int h = c0 + c;
  int orow = interleave ? (32 * (h >> 4) + 16 * s + (h & 15)) : h;
  ushort4 u;
  u.x = f2bf(tile[q * 4 + 0][c]); u.y = f2bf(tile[q * 4 + 1][c]);
  u.z = f2bf(tile[q * 4 + 2][c]); u.w = f2bf(tile[q * 4 + 3][c]);
  *(ushort4*)&op[(size_t)orow * R + r0 + q * 4] = u;
}

// ---- W1/W3 -> interleaved W13t (critical path to ffn_a, own launch) ----
__global__ void tcast_w13_kernel(const float* __restrict__ W1, const float* __restrict__ W3,
                                 unsigned short* __restrict__ W13t) {
  __shared__ float tile[32][33];
  int b = blockIdx.x;
  int z = b >> 11, rem = b & 2047;
  int e = z & 7, s = z >> 3;
  tc_tile((s ? W3 : W1) + (size_t)e * DIM * HID, HID,
          W13t + (size_t)e * 2 * HID * DIM, DIM,
          (rem & 63) * 32, (rem >> 6) * 32, tile, 1, s);
}

// ---------------- gating + fused X cast + per-block histogram (256 blocks x 16 tok) ----
__global__ __launch_bounds__(256) void gating_kernel(
    const float* __restrict__ X, const float* __restrict__ Wg,
    const float* __restrict__ bg, unsigned short* __restrict__ Xb,
    int* __restrict__ topk_pack, float* __restrict__ topk_w,
    int* __restrict__ blkcnt) {
  __shared__ float wgs[NE][DIM];
  __shared__ int hist[NE];
  const int tid = threadIdx.x;
  for (int d = tid; d < DIM; d += 256) {
#pragma unroll
    for (int e = 0; e < NE; e++) wgs[e][d] = Wg[d * NE + e];
  }
  if (tid < NE) hist[tid] = 0;
  __syncthreads();
  const int wave = tid >> 6, lane = tid & 63;
  for (int tk = wave; tk < 16; tk += 4) {
    const int t = blockIdx.x * 16 + tk;
    const float* xr = X + (size_t)t * DIM;
    {
      const float4* xp = (const float4*)(xr + lane * 16);
      float4 v0 = xp[0], v1 = xp[1], v2 = xp[2], v3 = xp[3];
      uint4 w0, w1;
      w0.x = f2bf(v0.x) | ((unsigned)f2bf(v0.y) << 16);
      w0.y = f2bf(v0.z) | ((unsigned)f2bf(v0.w) << 16);
      w0.z = f2bf(v1.x) | ((unsigned)f2bf(v1.y) << 16);
      w0.w = f2bf(v1.z) | ((unsigned)f2bf(v1.w) << 16);
      w1.x = f2bf(v2.x) | ((unsigned)f2bf(v2.y) << 16);
      w1.y = f2bf(v2.z) | ((unsigned)f2bf(v2.w) << 16);
      w1.z = f2bf(v3.x) | ((unsigned)f2bf(v3.y) << 16);
      w1.w = f2bf(v3.z) | ((unsigned)f2bf(v3.w) << 16);
      uint4* op2 = (uint4*)(Xb + (size_t)t * DIM + lane * 16);
      op2[0] = w0; op2[1] = w1;
    }
    float acc[NE];
#pragma unroll
    for (int e = 0; e < NE; e++) acc[e] = 0.f;
#pragma unroll
    for (int j = 0; j < 16; j++) {
      float xv = xr[lane + j * 64];
#pragma unroll
      for (int e = 0; e < NE; e++) acc[e] += xv * wgs[e][lane + j * 64];
    }
#pragma unroll
    for (int e = 0; e < NE; e++) {
#pragma unroll
      for (int off = 32; off > 0; off >>= 1) acc[e] += __shfl_xor(acc[e], off, 64);
    }
    if (lane == 0) {
      float p[NE];
      float mx = -1e30f;
#pragma unroll
      for (int e = 0; e < NE; e++) { p[e] = acc[e] + bg[e]; mx = fmaxf(mx, p[e]); }
      float sum = 0.f;
#pragma unroll
      for (int e = 0; e < NE; e++) { p[e] = expf(p[e] - mx); sum += p[e]; }
      float inv = 1.f / sum;
#pragma unroll
      for (int e = 0; e < NE; e++) p[e] *= inv;
      int i1 = 0; float v1 = p[0];
#pragma unroll
      for (int e = 1; e < NE; e++) if (p[e] >= v1) { v1 = p[e]; i1 = e; }
      int i2 = (i1 == 0) ? 1 : 0; float v2 = p[i2];
#pragma unroll
      for (int e = 0; e < NE; e++) {
        if (e == i1) continue;
        if (p[e] >= v2 && e != i2) { v2 = p[e]; i2 = e; }
      }
      topk_pack[t] = i1 | (i2 << 4);
      topk_w[t * 2 + 0] = v1; topk_w[t * 2 + 1] = v2;
      atomicAdd(&hist[i1], 1); atomicAdd(&hist[i2], 1);
    }
  }
  __syncthreads();
  if (tid < NE) blkcnt[blockIdx.x * NE + tid] = hist[tid];
}

// ------- scatter with integrated prefix (256 gating blocks; lane scans 4) -------
__global__ void scatter_kernel(const int* __restrict__ blkcnt,
                               const int* __restrict__ topk_pack,
                               int* __restrict__ counts, int* __restrict__ row_start,
                               int* __restrict__ tp, int* __restrict__ list) {
  __shared__ int lofs[NE];
  const int lane = threadIdx.x;   // 64
  const int myb = blockIdx.x;     // 256
  int s = 0, t = 0;
#pragma unroll
  for (int e = 0; e < NE; e++) {
    int tote = 0, pre = 0;
#pragma unroll
    for (int j = 0; j < 4; j++) {
      int b = lane * 4 + j;
      int c = blkcnt[b * NE + e];
      tote += c;
      if (b < myb) pre += c;
    }
#pragma unroll
    for (int off = 32; off > 0; off >>= 1) {
      tote += __shfl_xor(tote, off, 64);
      pre  += __shfl_xor(pre,  off, 64);
    }
    if (lane == 0) lofs[e] = s + pre;
    if (myb == 0 && lane == 0) { counts[e] = tote; row_start[e] = s; tp[e] = t; }
    s += tote; t += (tote + 127) >> 7;
  }
  if (myb == 0 && lane == 0) tp[NE] = t;
  __syncthreads();
  if (lane < 16) {
    int tok = myb * 16 + lane;
    int pk = topk_pack[tok];
    int e1 = pk & 15, e2 = (pk >> 4) & 15;
    int p1 = atomicAdd(&lofs[e1], 1); list[p1] = tok << 1;
    int p2 = atomicAdd(&lofs[e2], 1); list[p2] = (tok << 1) | 1;
  }
}

// ==== stage A (R6/R12-proven 128x128 m97 loop) + trailing W2t/Wf cast blocks ====
#define FFNA_BLKS 2304   // 72 m-tiles x 32 n-tiles (bid = by*32 + bx)
#define W2T_BLKS  16384
__global__ __launch_bounds__(256, 3) void ffn_a_kernel(
    const unsigned short* __restrict__ Xb,
    const unsigned short* __restrict__ W13t,
    const float* __restrict__ b1, const float* __restrict__ b3,
    const float* __restrict__ W2, const float* __restrict__ Wf,
    unsigned short* __restrict__ W2t, unsigned short* __restrict__ Wft,
    const int* __restrict__ counts, const int* __restrict__ row_start,
    const int* __restrict__ tp, const int* __restrict__ list,
    unsigned short* __restrict__ h_buf) {
  __shared__ unsigned short As[128 * 64];
  __shared__ unsigned short Bs[128 * 64];
  const int bid = blockIdx.x;
  if (bid >= FFNA_BLKS) {
    int i = bid - FFNA_BLKS;
    if (i < W2T_BLKS) {
      int z = i >> 11, rem = i & 2047;
      tc_tile(W2 + (size_t)z * HID * OUTD, OUTD, W2t + (size_t)z * OUTD * HID, HID,
              (rem & 31) * 32, (rem >> 5) * 32, (float(*)[33])As, 0, 0);
    } else {
      int i2 = i - W2T_BLKS;
      tc_tile(Wf, OUTD, Wft, DIM, (i2 & 31) * 32, (i2 >> 5) * 32,
              (float(*)[33])As, 0, 0);
    }
    return;
  }
  const int by = bid >> 5;
  if (by >= tp[NE]) return;
  int e = 0;
#pragma unroll
  for (int k = 1; k < NE; k++) if (by >= tp[k]) e = k;
  const int ne = counts[e], rs = row_start[e];
  const int m0 = (by - tp[e]) * 128;
  const int n0 = (bid & 31) * 128;           // interleaved col space [0,4096)

  const int tid = threadIdx.x;
  const int wave = tid >> 6, lane = tid & 63;
  const int lr = lane & 15, lk = lane >> 4;
  const int wm = (wave >> 1) * 64, wn = (wave & 1) * 64;

  // staging rows (wave*4+i)*8 + (lane>>3), slot lane&7 (128B rows)
  // LDS slot q of row r holds global col16 (q ^ (r&7))   [conflict-free, R6-proven]
  const int scs = ((lane & 7) ^ (lane >> 3)) * 8;
  const unsigned short* asrc[4];
  const unsigned short* bsrc[4];
#pragma unroll
  for (int i = 0; i < 4; i++) {
    int sr = (wave * 4 + i) * 8 + (lane >> 3);
    int rr = m0 + sr; if (rr >= ne) rr = m0;
    int tok = list[rs + rr] >> 1;
    asrc[i] = Xb + (size_t)tok * DIM + scs;
    bsrc[i] = W13t + ((size_t)e * 2 * HID + n0 + sr) * DIM + scs;
  }

  f32x4 acc[4][4];
  const f32x4 zero = {0.f, 0.f, 0.f, 0.f};
#pragma unroll
  for (int m = 0; m < 4; m++)
#pragma unroll
    for (int n = 0; n < 4; n++) acc[m][n] = zero;

  const int sx = lr & 7;

  for (int k0 = 0; k0 < DIM; k0 += 64) {
#pragma unroll
    for (int i = 0; i < 4; i++) {
      gload16(asrc[i] + k0, &As[(wave * 4 + i) * 512]);
      gload16(bsrc[i] + k0, &Bs[(wave * 4 + i) * 512]);
    }
    __syncthreads();
#pragma unroll
    for (int kk = 0; kk < 2; kk++) {
      const int sl = ((kk * 4 + lk) ^ sx) * 8;
      bf16x8 a[4], b[4];
#pragma unroll
      for (int m = 0; m < 4; m++)
        a[m] = *(const bf16x8*)&As[(wm + m * 16 + lr) * 64 + sl];
#pragma unroll
      for (int n = 0; n < 4; n++)
        b[n] = *(const bf16x8*)&Bs[(wn + n * 16 + lr) * 64 + sl];
#pragma unroll
      for (int m = 0; m < 4; m++)
#pragma unroll
        for (int n = 0; n < 4; n++)
          acc[m][n] = __builtin_amdgcn_mfma_f32_16x16x32_bf16(a[m], b[n], acc[m][n], 0, 0, 0);
    }
    __syncthreads();
  }

  // SwiGLU epilogue: frag pair (2g,2g+1) = (h1,h3); h = ((n0+wn)>>5 + g)*16 + lr
  const int hq = (n0 + wn) >> 5;
#pragma unroll
  for (int g = 0; g < 2; g++) {
    int h = (hq + g) * 16 + lr;
    float b1v = b1[e * HID + h];
    float b3v = b3[e * HID + h];
#pragma unroll
    for (int m = 0; m < 4; m++) {
#pragma unroll
      for (int j = 0; j < 4; j++) {
        int rr = m0 + wm + m * 16 + lk * 4 + j;
        if (rr < ne) {
          float h1 = acc[m][2 * g][j] + b1v;
          float h3 = acc[m][2 * g + 1][j] + b3v;
          float v = h1 * h3;
          h_buf[(size_t)(rs + rr) * HID + h] = f2bf(v / (1.f + expf(-v)));
        }
      }
    }
  }
}

// ============ stage B: 128x128, BK=64, m97 single-buffer, bf16 out (proven) ============
__global__ __launch_bounds__(256, 3) void ffn_b_kernel(
    const unsigned short* __restrict__ h_buf,
    const unsigned short* __restrict__ W2t,
    const float* __restrict__ b2,
    const int* __restrict__ counts, const int* __restrict__ row_start,
    const int* __restrict__ tp, const int* __restrict__ list,
    const float* __restrict__ topk_w, unsigned short* __restrict__ ob) {
  __shared__ unsigned short As[128 * 64];
  __shared__ unsigned short Bs[128 * 64];
  const int by = blockIdx.y;
  if (by >= tp[NE]) return;
  int e = 0;
#pragma unroll
  for (int k = 1; k < NE; k++) if (by >= tp[k]) e = k;
  const int ne = counts[e], rs = row_start[e];
  const int m0 = (by - tp[e]) * 128;
  const int n0 = blockIdx.x * 128;

  const int tid = threadIdx.x;
  const int wave = tid >> 6, lane = tid & 63;
  const int lr = lane & 15, lk = lane >> 4;
  const int wm = (wave >> 1) * 64, wn = (wave & 1) * 64;

  const int scs = ((lane & 7) ^ (lane >> 3)) * 8;
  const unsigned short* asrc[4];
  const unsigned short* bsrc[4];
#pragma unroll
  for (int i = 0; i < 4; i++) {
    int sr = (wave * 4 + i) * 8 + (lane >> 3);
    asrc[i] = h_buf + (size_t)(rs + m0 + sr) * HID + scs;   // padded rows, in-bounds
    bsrc[i] = W2t + ((size_t)e * OUTD + n0 + sr) * HID + scs;
  }

  f32x4 acc[4][4];
  const f32x4 zero = {0.f, 0.f, 0.f, 0.f};
#pragma unroll
  for (int m = 0; m < 4; m++)
#pragma unroll
    for (int n = 0; n < 4; n++) acc[m][n] = zero;

  const int sx = lr & 7;

  for (int k0 = 0; k0 < HID; k0 += 64) {
#pragma unroll
    for (int i = 0; i < 4; i++) {
      gload16(asrc[i] + k0, &As[(wave * 4 + i) * 512]);
      gload16(bsrc[i] + k0, &Bs[(wave * 4 + i) * 512]);
    }
    __syncthreads();
#pragma unroll
    for (int kk = 0; kk < 2; kk++) {
      const int sl = ((kk * 4 + lk) ^ sx) * 8;
      bf16x8 a[4], b[4];
#pragma unroll
      for (int m = 0; m < 4; m++)
        a[m] = *(const bf16x8*)&As[(wm + m * 16 + lr) * 64 + sl];
#pragma unroll
      for (int n = 0; n < 4; n++)
        b[n] = *(const bf16x8*)&Bs[(wn + n * 16 + lr) * 64 + sl];
#pragma unroll
      for (int m = 0; m < 4; m++)
#pragma unroll
        for (int n = 0; n < 4; n++)
          acc[m][n] = __builtin_amdgcn_mfma_f32_16x16x32_bf16(a[m], b[n], acc[m][n], 0, 0, 0);
    }
    __syncthreads();
  }

#pragma unroll
  for (int n = 0; n < 4; n++) {
    int col = n0 + wn + n * 16 + lr;
    float b2v = b2[e * OUTD + col];
#pragma unroll
    for (int m = 0; m < 4; m++) {
#pragma unroll
      for (int j = 0; j < 4; j++) {
        int rr = m0 + wm + m * 16 + lk * 4 + j;
        if (rr < ne) {
          int entry = list[rs + rr];
          float w = topk_w[entry];
          ob[(size_t)entry * OUTD + col] = f2bf(w * (acc[m][n][j] + b2v));
        }
      }
    }
  }
}

// ---------------- final: out = (ob0 + ob1) @ Wf + bf ; XCD-grouped m-bands ----------------
__global__ __launch_bounds__(256) void final_kernel(
    const unsigned short* __restrict__ ob, const unsigned short* __restrict__ Wft,
    const float* __restrict__ bfv, float* __restrict__ out) {
  const int bid = blockIdx.x;
  const int n0 = (bid >> 5) * 128;
  const int m0 = ((bid & 7) + 8 * ((bid >> 3) & 3)) * 128;

  __shared__ unsigned short As[128 * 64];
  __shared__ unsigned short Bs[128 * 64];

  const int tid = threadIdx.x;
  const int wave = tid >> 6, lane = tid & 63;
  const int lrow = lane >> 3;
  const int lcol = (lane & 7) * 8;

  const unsigned short* bsrc[4];
#pragma unroll
  for (int i = 0; i < 4; i++) {
    int sr = (wave * 4 + i) * 8 + lrow;
    bsrc[i] = Wft + (size_t)(n0 + sr) * DIM + lcol;
  }

  const int wm = (wave >> 1) * 64, wn = (wave & 1) * 64;
  const int lr = lane & 15, lk = lane >> 4;

  f32x4 acc[4][4];
  const f32x4 zero = {0.f, 0.f, 0.f, 0.f};
#pragma unroll
  for (int m = 0; m < 4; m++)
#pragma unroll
    for (int n = 0; n < 4; n++) acc[m][n] = zero;

  for (int k0 = 0; k0 < DIM; k0 += 64) {
#pragma unroll
    for (int g = 0; g < 8; g++) {
      int idx = g * 256 + tid;
      int r = idx >> 4;
      int c4 = (idx & 15) * 4;
      ushort4 a0 = *(const ushort4*)&ob[((size_t)(m0 + r) * 2) * OUTD + k0 + c4];
      ushort4 a1 = *(const ushort4*)&ob[((size_t)(m0 + r) * 2 + 1) * OUTD + k0 + c4];
      ushort4 u;
      u.x = f2bf(b2f(a0.x) + b2f(a1.x)); u.y = f2bf(b2f(a0.y) + b2f(a1.y));
      u.z = f2bf(b2f(a0.z) + b2f(a1.z)); u.w = f2bf(b2f(a0.w) + b2f(a1.w));
      *(ushort4*)&As[r * 64 + c4] = u;
    }
#pragma unroll
    for (int i = 0; i < 4; i++) gload16(bsrc[i] + k0, &Bs[(wave * 4 + i) * 512]);
    __syncthreads();
#pragma unroll
    for (int kk = 0; kk < 2; kk++) {
      bf16x8 a[4], b[4];
#pragma unroll
      for (int m = 0; m < 4; m++)
        a[m] = *(const bf16x8*)&As[(wm + m * 16 + lr) * 64 + kk * 32 + lk * 8];
#pragma unroll
      for (int n = 0; n < 4; n++)
        b[n] = *(const bf16x8*)&Bs[(wn + n * 16 + lr) * 64 + kk * 32 + lk * 8];
#pragma unroll
      for (int m = 0; m < 4; m++)
#pragma unroll
        for (int n = 0; n < 4; n++)
          acc[m][n] = __builtin_amdgcn_mfma_f32_16x16x32_bf16(a[m], b[n], acc[m][n], 0, 0, 0);
    }
    __syncthreads();
  }

#pragma unroll
  for (int n = 0; n < 4; n++) {
    int col = n0 + wn + n * 16 + lr;
    float bv = bfv[col];
#pragma unroll
    for (int m = 0; m < 4; m++) {
#pragma unroll
      for (int j = 0; j < 4; j++) {
        int r = m0 + wm + m * 16 + lk * 4 + j;
        out[(size_t)r * OUTD + col] = acc[m][n][j] + bv;
      }
    }
  }
}

extern "C" void kernel_launch(void* const* d_in, const int* in_sizes, int n_in,
                              void* d_out, int out_size, void* d_ws, size_t ws_size,
                              hipStream_t stream) {
  const float* X   = (const float*)d_in[0];
  const float* W1  = (const float*)d_in[1];
  const float* b1  = (const float*)d_in[2];
  const float* W3  = (const float*)d_in[3];
  const float* b3  = (const float*)d_in[4];
  const float* W2  = (const float*)d_in[5];
  const float* b2  = (const float*)d_in[6];
  const float* Wg  = (const float*)d_in[7];
  const float* bg  = (const float*)d_in[8];
  const float* Wf  = (const float*)d_in[9];
  const float* bfv = (const float*)d_in[10];
  float* out = (float*)d_out;

  char* p = (char*)d_ws;
  auto alloc = [&](size_t bytes) { char* r = p; p += (bytes + 255) & ~(size_t)255; return r; };
  unsigned short* Xb   = (unsigned short*)alloc((size_t)NTOK * DIM * 2);
  unsigned short* W13t = (unsigned short*)alloc((size_t)NE * 2 * HID * DIM * 2);
  unsigned short* W2t  = (unsigned short*)alloc((size_t)NE * OUTD * HID * 2);
  unsigned short* Wft  = (unsigned short*)alloc((size_t)OUTD * DIM * 2);
  unsigned short* hbuf = (unsigned short*)alloc((size_t)(NTOK * 2 + 256) * HID * 2);
  unsigned short* ob   = (unsigned short*)alloc((size_t)NTOK * 2 * OUTD * 2);
  int* topk_pack       = (int*)alloc(NTOK * 4);
  float* topk_w        = (float*)alloc(NTOK * 2 * 4);
  int* counts          = (int*)alloc(NE * 4);
  int* row_start       = (int*)alloc(NE * 4);
  int* tp              = (int*)alloc((NE + 1) * 4);
  int* blkcnt          = (int*)alloc(256 * NE * 4);
  int* list            = (int*)alloc(NTOK * 2 * 4);

  gating_kernel<<<256, 256, 0, stream>>>(X, Wg, bg, Xb, topk_pack, topk_w, blkcnt);
  tcast_w13_kernel<<<32768, 256, 0, stream>>>(W1, W3, W13t);

  scatter_kernel<<<256, 64, 0, stream>>>(blkcnt, topk_pack, counts, row_start, tp, list);

  // ffn_a GEMM (2304) + W2t cast (16384) + Wf cast (1024)
  ffn_a_kernel<<<FFNA_BLKS + W2T_BLKS + 1024, 256, 0, stream>>>(
      Xb, W13t, b1, b3, W2, Wf, W2t, Wft, counts, row_start, tp, list, hbuf);
  // ffn_b: 128x128 tiles
  ffn_b_kernel<<<dim3(OUTD / 128, 72), 256, 0, stream>>>(
      hbuf, W2t, b2, counts, row_start, tp, list, topk_w, ob);
  final_kernel<<<256, 256, 0, stream>>>(ob, Wft, bfv, out);
}

// Round 14
// 277.082 us; speedup vs baseline: 3.6578x; 1.0150x over previous
//
#include <hip/hip_runtime.h>

#define DIM  1024
#define HID  2048
#define OUTD 1024
#define NE   8
#define NTOK 4096

using bf16x8 = __attribute__((ext_vector_type(8))) short;
using f32x4  = __attribute__((ext_vector_type(4))) float;

__device__ __forceinline__ unsigned short f2bf(float f) {
  unsigned int u = __builtin_bit_cast(unsigned int, f);
  u += 0x7fff + ((u >> 16) & 1);   // round-to-nearest-even
  return (unsigned short)(u >> 16);
}
__device__ __forceinline__ float b2f(unsigned short u) {
  unsigned int v = (unsigned int)u << 16;
  return __builtin_bit_cast(float, v);
}

__device__ __forceinline__ void gload16(const void* g, void* l) {
  __builtin_amdgcn_global_load_lds(
      (const __attribute__((address_space(1))) void*)g,
      (__attribute__((address_space(3))) void*)l, 16, 0, 0);
}

// ---- shared 32x32 transpose-cast tile body ----
__device__ __forceinline__ void tc_tile(const float* __restrict__ inp, int C,
                                        unsigned short* __restrict__ op, int R,
                                        int c0, int r0, float (*tile)[33],
                                        int interleave, int s) {
  int tx = threadIdx.x & 31, ty = threadIdx.x >> 5;
#pragma unroll
  for (int j = 0; j < 4; j++)
    tile[ty + j * 8][tx] = inp[(size_t)(r0 + ty + j * 8) * C + c0 + tx];
  __syncthreads();
  int c = threadIdx.x >> 3, q = threadIdx.x & 7;
  int h = c0 + c;
  int orow = interleave ? (32 * (h >> 4) + 16 * s + (h & 15)) : h;
  ushort4 u;
  u.x = f2bf(tile[q * 4 + 0][c]); u.y = f2bf(tile[q * 4 + 1][c]);
  u.z = f2bf(tile[q * 4 + 2][c]); u.w = f2bf(tile[q * 4 + 3][c]);
  *(ushort4*)&op[(size_t)orow * R + r0 + q * 4] = u;
}

// ==== K1: fused gating (+X cast, blocks 0..255) + W13t transpose-cast (blocks 256..33023)
__global__ __launch_bounds__(256) void prep_kernel(
    const float* __restrict__ X, const float* __restrict__ Wg,
    const float* __restrict__ bg, const float* __restrict__ W1,
    const float* __restrict__ W3, unsigned short* __restrict__ Xb,
    unsigned short* __restrict__ W13t, int* __restrict__ topk_pack,
    float* __restrict__ topk_w, int* __restrict__ blkcnt) {
  __shared__ float smem[NE * DIM + NE];   // 32KB + hist
  const int b = blockIdx.x;
  if (b >= 256) {
    // W13t cast: i in [0, 32768)
    int i = b - 256;
    int z = i >> 11, rem = i & 2047;
    int e = z & 7, s = z >> 3;
    tc_tile((s ? W3 : W1) + (size_t)e * DIM * HID, HID,
            W13t + (size_t)e * 2 * HID * DIM, DIM,
            (rem & 63) * 32, (rem >> 6) * 32, (float(*)[33])smem, 1, s);
    return;
  }
  float (*wgs)[DIM] = (float(*)[DIM])smem;
  int* hist = (int*)&smem[NE * DIM];
  const int tid = threadIdx.x;
  for (int d = tid; d < DIM; d += 256) {
#pragma unroll
    for (int e = 0; e < NE; e++) wgs[e][d] = Wg[d * NE + e];
  }
  if (tid < NE) hist[tid] = 0;
  __syncthreads();
  const int wave = tid >> 6, lane = tid & 63;
  for (int tk = wave; tk < 16; tk += 4) {
    const int t = b * 16 + tk;
    const float* xr = X + (size_t)t * DIM;
    {
      const float4* xp = (const float4*)(xr + lane * 16);
      float4 v0 = xp[0], v1 = xp[1], v2 = xp[2], v3 = xp[3];
      uint4 w0, w1;
      w0.x = f2bf(v0.x) | ((unsigned)f2bf(v0.y) << 16);
      w0.y = f2bf(v0.z) | ((unsigned)f2bf(v0.w) << 16);
      w0.z = f2bf(v1.x) | ((unsigned)f2bf(v1.y) << 16);
      w0.w = f2bf(v1.z) | ((unsigned)f2bf(v1.w) << 16);
      w1.x = f2bf(v2.x) | ((unsigned)f2bf(v2.y) << 16);
      w1.y = f2bf(v2.z) | ((unsigned)f2bf(v2.w) << 16);
      w1.z = f2bf(v3.x) | ((unsigned)f2bf(v3.y) << 16);
      w1.w = f2bf(v3.z) | ((unsigned)f2bf(v3.w) << 16);
      uint4* op2 = (uint4*)(Xb + (size_t)t * DIM + lane * 16);
      op2[0] = w0; op2[1] = w1;
    }
    float acc[NE];
#pragma unroll
    for (int e = 0; e < NE; e++) acc[e] = 0.f;
#pragma unroll
    for (int j = 0; j < 16; j++) {
      float xv = xr[lane + j * 64];
#pragma unroll
      for (int e = 0; e < NE; e++) acc[e] += xv * wgs[e][lane + j * 64];
    }
#pragma unroll
    for (int e = 0; e < NE; e++) {
#pragma unroll
      for (int off = 32; off > 0; off >>= 1) acc[e] += __shfl_xor(acc[e], off, 64);
    }
    if (lane == 0) {
      float p[NE];
      float mx = -1e30f;
#pragma unroll
      for (int e = 0; e < NE; e++) { p[e] = acc[e] + bg[e]; mx = fmaxf(mx, p[e]); }
      float sum = 0.f;
#pragma unroll
      for (int e = 0; e < NE; e++) { p[e] = expf(p[e] - mx); sum += p[e]; }
      float inv = 1.f / sum;
#pragma unroll
      for (int e = 0; e < NE; e++) p[e] *= inv;
      int i1 = 0; float v1 = p[0];
#pragma unroll
      for (int e = 1; e < NE; e++) if (p[e] >= v1) { v1 = p[e]; i1 = e; }
      int i2 = (i1 == 0) ? 1 : 0; float v2 = p[i2];
#pragma unroll
      for (int e = 0; e < NE; e++) {
        if (e == i1) continue;
        if (p[e] >= v2 && e != i2) { v2 = p[e]; i2 = e; }
      }
      topk_pack[t] = i1 | (i2 << 4);
      topk_w[t * 2 + 0] = v1; topk_w[t * 2 + 1] = v2;
      atomicAdd(&hist[i1], 1); atomicAdd(&hist[i2], 1);
    }
  }
  __syncthreads();
  if (tid < NE) blkcnt[b * NE + tid] = hist[tid];
}

// ------- scatter with integrated prefix (256 gating blocks; lane scans 4) -------
__global__ void scatter_kernel(const int* __restrict__ blkcnt,
                               const int* __restrict__ topk_pack,
                               int* __restrict__ counts, int* __restrict__ row_start,
                               int* __restrict__ tp, int* __restrict__ list) {
  __shared__ int lofs[NE];
  const int lane = threadIdx.x;   // 64
  const int myb = blockIdx.x;     // 256
  int s = 0, t = 0;
#pragma unroll
  for (int e = 0; e < NE; e++) {
    int tote = 0, pre = 0;
#pragma unroll
    for (int j = 0; j < 4; j++) {
      int b = lane * 4 + j;
      int c = blkcnt[b * NE + e];
      tote += c;
      if (b < myb) pre += c;
    }
#pragma unroll
    for (int off = 32; off > 0; off >>= 1) {
      tote += __shfl_xor(tote, off, 64);
      pre  += __shfl_xor(pre,  off, 64);
    }
    if (lane == 0) lofs[e] = s + pre;
    if (myb == 0 && lane == 0) { counts[e] = tote; row_start[e] = s; tp[e] = t; }
    s += tote; t += (tote + 127) >> 7;
  }
  if (myb == 0 && lane == 0) tp[NE] = t;
  __syncthreads();
  if (lane < 16) {
    int tok = myb * 16 + lane;
    int pk = topk_pack[tok];
    int e1 = pk & 15, e2 = (pk >> 4) & 15;
    int p1 = atomicAdd(&lofs[e1], 1); list[p1] = tok << 1;
    int p2 = atomicAdd(&lofs[e2], 1); list[p2] = (tok << 1) | 1;
  }
}

// ==== stage A (proven 128x128 m97 loop) + trailing W2t/Wf cast blocks ====
#define FFNA_BLKS 2304   // 72 m-tiles x 32 n-tiles (bid = by*32 + bx)
#define W2T_BLKS  16384
__global__ __launch_bounds__(256, 3) void ffn_a_kernel(
    const unsigned short* __restrict__ Xb,
    const unsigned short* __restrict__ W13t,
    const float* __restrict__ b1, const float* __restrict__ b3,
    const float* __restrict__ W2, const float* __restrict__ Wf,
    unsigned short* __restrict__ W2t, unsigned short* __restrict__ Wft,
    const int* __restrict__ counts, const int* __restrict__ row_start,
    const int* __restrict__ tp, const int* __restrict__ list,
    unsigned short* __restrict__ h_buf) {
  __shared__ unsigned short As[128 * 64];
  __shared__ unsigned short Bs[128 * 64];
  const int bid = blockIdx.x;
  if (bid >= FFNA_BLKS) {
    int i = bid - FFNA_BLKS;
    if (i < W2T_BLKS) {
      int z = i >> 11, rem = i & 2047;
      tc_tile(W2 + (size_t)z * HID * OUTD, OUTD, W2t + (size_t)z * OUTD * HID, HID,
              (rem & 31) * 32, (rem >> 5) * 32, (float(*)[33])As, 0, 0);
    } else {
      int i2 = i - W2T_BLKS;
      tc_tile(Wf, OUTD, Wft, DIM, (i2 & 31) * 32, (i2 >> 5) * 32,
              (float(*)[33])As, 0, 0);
    }
    return;
  }
  const int by = bid >> 5;
  if (by >= tp[NE]) return;
  int e = 0;
#pragma unroll
  for (int k = 1; k < NE; k++) if (by >= tp[k]) e = k;
  const int ne = counts[e], rs = row_start[e];
  const int m0 = (by - tp[e]) * 128;
  const int n0 = (bid & 31) * 128;           // interleaved col space [0,4096)

  const int tid = threadIdx.x;
  const int wave = tid >> 6, lane = tid & 63;
  const int lr = lane & 15, lk = lane >> 4;
  const int wm = (wave >> 1) * 64, wn = (wave & 1) * 64;

  const int scs = ((lane & 7) ^ (lane >> 3)) * 8;
  const unsigned short* asrc[4];
  const unsigned short* bsrc[4];
#pragma unroll
  for (int i = 0; i < 4; i++) {
    int sr = (wave * 4 + i) * 8 + (lane >> 3);
    int rr = m0 + sr; if (rr >= ne) rr = m0;
    int tok = list[rs + rr] >> 1;
    asrc[i] = Xb + (size_t)tok * DIM + scs;
    bsrc[i] = W13t + ((size_t)e * 2 * HID + n0 + sr) * DIM + scs;
  }

  f32x4 acc[4][4];
  const f32x4 zero = {0.f, 0.f, 0.f, 0.f};
#pragma unroll
  for (int m = 0; m < 4; m++)
#pragma unroll
    for (int n = 0; n < 4; n++) acc[m][n] = zero;

  const int sx = lr & 7;

  for (int k0 = 0; k0 < DIM; k0 += 64) {
#pragma unroll
    for (int i = 0; i < 4; i++) {
      gload16(asrc[i] + k0, &As[(wave * 4 + i) * 512]);
      gload16(bsrc[i] + k0, &Bs[(wave * 4 + i) * 512]);
    }
    __syncthreads();
#pragma unroll
    for (int kk = 0; kk < 2; kk++) {
      const int sl = ((kk * 4 + lk) ^ sx) * 8;
      bf16x8 a[4], b[4];
#pragma unroll
      for (int m = 0; m < 4; m++)
        a[m] = *(const bf16x8*)&As[(wm + m * 16 + lr) * 64 + sl];
#pragma unroll
      for (int n = 0; n < 4; n++)
        b[n] = *(const bf16x8*)&Bs[(wn + n * 16 + lr) * 64 + sl];
#pragma unroll
      for (int m = 0; m < 4; m++)
#pragma unroll
        for (int n = 0; n < 4; n++)
          acc[m][n] = __builtin_amdgcn_mfma_f32_16x16x32_bf16(a[m], b[n], acc[m][n], 0, 0, 0);
    }
    __syncthreads();
  }

  // SwiGLU epilogue: frag pair (2g,2g+1) = (h1,h3); h = ((n0+wn)>>5 + g)*16 + lr
  const int hq = (n0 + wn) >> 5;
#pragma unroll
  for (int g = 0; g < 2; g++) {
    int h = (hq + g) * 16 + lr;
    float b1v = b1[e * HID + h];
    float b3v = b3[e * HID + h];
#pragma unroll
    for (int m = 0; m < 4; m++) {
#pragma unroll
      for (int j = 0; j < 4; j++) {
        int rr = m0 + wm + m * 16 + lk * 4 + j;
        if (rr < ne) {
          float h1 = acc[m][2 * g][j] + b1v;
          float h3 = acc[m][2 * g + 1][j] + b3v;
          float v = h1 * h3;
          h_buf[(size_t)(rs + rr) * HID + h] = f2bf(v / (1.f + expf(-v)));
        }
      }
    }
  }
}

// ============ stage B: 128x128, BK=64, m97 single-buffer, bf16 out (proven) ============
__global__ __launch_bounds__(256, 3) void ffn_b_kernel(
    const unsigned short* __restrict__ h_buf,
    const unsigned short* __restrict__ W2t,
    const float* __restrict__ b2,
    const int* __restrict__ counts, const int* __restrict__ row_start,
    const int* __restrict__ tp, const int* __restrict__ list,
    const float* __restrict__ topk_w, unsigned short* __restrict__ ob) {
  __shared__ unsigned short As[128 * 64];
  __shared__ unsigned short Bs[128 * 64];
  const int by = blockIdx.y;
  if (by >= tp[NE]) return;
  int e = 0;
#pragma unroll
  for (int k = 1; k < NE; k++) if (by >= tp[k]) e = k;
  const int ne = counts[e], rs = row_start[e];
  const int m0 = (by - tp[e]) * 128;
  const int n0 = blockIdx.x * 128;

  const int tid = threadIdx.x;
  const int wave = tid >> 6, lane = tid & 63;
  const int lr = lane & 15, lk = lane >> 4;
  const int wm = (wave >> 1) * 64, wn = (wave & 1) * 64;

  const int scs = ((lane & 7) ^ (lane >> 3)) * 8;
  const unsigned short* asrc[4];
  const unsigned short* bsrc[4];
#pragma unroll
  for (int i = 0; i < 4; i++) {
    int sr = (wave * 4 + i) * 8 + (lane >> 3);
    asrc[i] = h_buf + (size_t)(rs + m0 + sr) * HID + scs;   // padded rows, in-bounds
    bsrc[i] = W2t + ((size_t)e * OUTD + n0 + sr) * HID + scs;
  }

  f32x4 acc[4][4];
  const f32x4 zero = {0.f, 0.f, 0.f, 0.f};
#pragma unroll
  for (int m = 0; m < 4; m++)
#pragma unroll
    for (int n = 0; n < 4; n++) acc[m][n] = zero;

  const int sx = lr & 7;

  for (int k0 = 0; k0 < HID; k0 += 64) {
#pragma unroll
    for (int i = 0; i < 4; i++) {
      gload16(asrc[i] + k0, &As[(wave * 4 + i) * 512]);
      gload16(bsrc[i] + k0, &Bs[(wave * 4 + i) * 512]);
    }
    __syncthreads();
#pragma unroll
    for (int kk = 0; kk < 2; kk++) {
      const int sl = ((kk * 4 + lk) ^ sx) * 8;
      bf16x8 a[4], b[4];
#pragma unroll
      for (int m = 0; m < 4; m++)
        a[m] = *(const bf16x8*)&As[(wm + m * 16 + lr) * 64 + sl];
#pragma unroll
      for (int n = 0; n < 4; n++)
        b[n] = *(const bf16x8*)&Bs[(wn + n * 16 + lr) * 64 + sl];
#pragma unroll
      for (int m = 0; m < 4; m++)
#pragma unroll
        for (int n = 0; n < 4; n++)
          acc[m][n] = __builtin_amdgcn_mfma_f32_16x16x32_bf16(a[m], b[n], acc[m][n], 0, 0, 0);
    }
    __syncthreads();
  }

#pragma unroll
  for (int n = 0; n < 4; n++) {
    int col = n0 + wn + n * 16 + lr;
    float b2v = b2[e * OUTD + col];
#pragma unroll
    for (int m = 0; m < 4; m++) {
#pragma unroll
      for (int j = 0; j < 4; j++) {
        int rr = m0 + wm + m * 16 + lk * 4 + j;
        if (rr < ne) {
          int entry = list[rs + rr];
          float w = topk_w[entry];
          ob[(size_t)entry * OUTD + col] = f2bf(w * (acc[m][n][j] + b2v));
        }
      }
    }
  }
}

// ---------------- final: out = (ob0 + ob1) @ Wf + bf ; XCD-grouped m-bands ----------------
__global__ __launch_bounds__(256) void final_kernel(
    const unsigned short* __restrict__ ob, const unsigned short* __restrict__ Wft,
    const float* __restrict__ bfv, float* __restrict__ out) {
  const int bid = blockIdx.x;
  const int n0 = (bid >> 5) * 128;
  const int m0 = ((bid & 7) + 8 * ((bid >> 3) & 3)) * 128;

  __shared__ unsigned short As[128 * 64];
  __shared__ unsigned short Bs[128 * 64];

  const int tid = threadIdx.x;
  const int wave = tid >> 6, lane = tid & 63;
  const int lrow = lane >> 3;
  const int lcol = (lane & 7) * 8;

  const unsigned short* bsrc[4];
#pragma unroll
  for (int i = 0; i < 4; i++) {
    int sr = (wave * 4 + i) * 8 + lrow;
    bsrc[i] = Wft + (size_t)(n0 + sr) * DIM + lcol;
  }

  const int wm = (wave >> 1) * 64, wn = (wave & 1) * 64;
  const int lr = lane & 15, lk = lane >> 4;

  f32x4 acc[4][4];
  const f32x4 zero = {0.f, 0.f, 0.f, 0.f};
#pragma unroll
  for (int m = 0; m < 4; m++)
#pragma unroll
    for (int n = 0; n < 4; n++) acc[m][n] = zero;

  for (int k0 = 0; k0 < DIM; k0 += 64) {
#pragma unroll
    for (int g = 0; g < 8; g++) {
      int idx = g * 256 + tid;
      int r = idx >> 4;
      int c4 = (idx & 15) * 4;
      ushort4 a0 = *(const ushort4*)&ob[((size_t)(m0 + r) * 2) * OUTD + k0 + c4];
      ushort4 a1 = *(const ushort4*)&ob[((size_t)(m0 + r) * 2 + 1) * OUTD + k0 + c4];
      ushort4 u;
      u.x = f2bf(b2f(a0.x) + b2f(a1.x)); u.y = f2bf(b2f(a0.y) + b2f(a1.y));
      u.z = f2bf(b2f(a0.z) + b2f(a1.z)); u.w = f2bf(b2f(a0.w) + b2f(a1.w));
      *(ushort4*)&As[r * 64 + c4] = u;
    }
#pragma unroll
    for (int i = 0; i < 4; i++) gload16(bsrc[i] + k0, &Bs[(wave * 4 + i) * 512]);
    __syncthreads();
#pragma unroll
    for (int kk = 0; kk < 2; kk++) {
      bf16x8 a[4], b[4];
#pragma unroll
      for (int m = 0; m < 4; m++)
        a[m] = *(const bf16x8*)&As[(wm + m * 16 + lr) * 64 + kk * 32 + lk * 8];
#pragma unroll
      for (int n = 0; n < 4; n++)
        b[n] = *(const bf16x8*)&Bs[(wn + n * 16 + lr) * 64 + kk * 32 + lk * 8];
#pragma unroll
      for (int m = 0; m < 4; m++)
#pragma unroll
        for (int n = 0; n < 4; n++)
          acc[m][n] = __builtin_amdgcn_mfma_f32_16x16x32_bf16(a[m], b[n], acc[m][n], 0, 0, 0);
    }
    __syncthreads();
  }

#pragma unroll
  for (int n = 0; n < 4; n++) {
    int col = n0 + wn + n * 16 + lr;
    float bv = bfv[col];
#pragma unroll
    for (int m = 0; m < 4; m++) {
#pragma unroll
      for (int j = 0; j < 4; j++) {
        int r = m0 + wm + m * 16 + lk * 4 + j;
        out[(size_t)r * OUTD + col] = acc[m][n][j] + bv;
      }
    }
  }
}

extern "C" void kernel_launch(void* const* d_in, const int* in_sizes, int n_in,
                              void* d_out, int out_size, void* d_ws, size_t ws_size,
                              hipStream_t stream) {
  const float* X   = (const float*)d_in[0];
  const float* W1  = (const float*)d_in[1];
  const float* b1  = (const float*)d_in[2];
  const float* W3  = (const float*)d_in[3];
  const float* b3  = (const float*)d_in[4];
  const float* W2  = (const float*)d_in[5];
  const float* b2  = (const float*)d_in[6];
  const float* Wg  = (const float*)d_in[7];
  const float* bg  = (const float*)d_in[8];
  const float* Wf  = (const float*)d_in[9];
  const float* bfv = (const float*)d_in[10];
  float* out = (float*)d_out;

  char* p = (char*)d_ws;
  auto alloc = [&](size_t bytes) { char* r = p; p += (bytes + 255) & ~(size_t)255; return r; };
  unsigned short* Xb   = (unsigned short*)alloc((size_t)NTOK * DIM * 2);
  unsigned short* W13t = (unsigned short*)alloc((size_t)NE * 2 * HID * DIM * 2);
  unsigned short* W2t  = (unsigned short*)alloc((size_t)NE * OUTD * HID * 2);
  unsigned short* Wft  = (unsigned short*)alloc((size_t)OUTD * DIM * 2);
  unsigned short* hbuf = (unsigned short*)alloc((size_t)(NTOK * 2 + 256) * HID * 2);
  unsigned short* ob   = (unsigned short*)alloc((size_t)NTOK * 2 * OUTD * 2);
  int* topk_pack       = (int*)alloc(NTOK * 4);
  float* topk_w        = (float*)alloc(NTOK * 2 * 4);
  int* counts          = (int*)alloc(NE * 4);
  int* row_start       = (int*)alloc(NE * 4);
  int* tp              = (int*)alloc((NE + 1) * 4);
  int* blkcnt          = (int*)alloc(256 * NE * 4);
  int* list            = (int*)alloc(NTOK * 2 * 4);

  // K1: gating (256) + W13t cast (32768)
  prep_kernel<<<256 + 32768, 256, 0, stream>>>(
      X, Wg, bg, W1, W3, Xb, W13t, topk_pack, topk_w, blkcnt);
  // K2: prefix + scatter
  scatter_kernel<<<256, 64, 0, stream>>>(blkcnt, topk_pack, counts, row_start, tp, list);
  // K3: ffn_a GEMM (2304) + W2t cast (16384) + Wf cast (1024)
  ffn_a_kernel<<<FFNA_BLKS + W2T_BLKS + 1024, 256, 0, stream>>>(
      Xb, W13t, b1, b3, W2, Wf, W2t, Wft, counts, row_start, tp, list, hbuf);
  // K4: ffn_b
  ffn_b_kernel<<<dim3(OUTD / 128, 72), 256, 0, stream>>>(
      hbuf, W2t, b2, counts, row_start, tp, list, topk_w, ob);
  // K5: final
  final_kernel<<<256, 256, 0, stream>>>(ob, Wft, bfv, out);
}

// Round 15
// 276.009 us; speedup vs baseline: 3.6720x; 1.0039x over previous
//
#include <hip/hip_runtime.h>

#define DIM  1024
#define HID  2048
#define OUTD 1024
#define NE   8
#define NTOK 4096

using bf16x8 = __attribute__((ext_vector_type(8))) short;
using f32x4  = __attribute__((ext_vector_type(4))) float;

__device__ __forceinline__ unsigned short f2bf(float f) {
  unsigned int u = __builtin_bit_cast(unsigned int, f);
  u += 0x7fff + ((u >> 16) & 1);   // round-to-nearest-even
  return (unsigned short)(u >> 16);
}
__device__ __forceinline__ float b2f(unsigned short u) {
  unsigned int v = (unsigned int)u << 16;
  return __builtin_bit_cast(float, v);
}

__device__ __forceinline__ void gload16(const void* g, void* l) {
  __builtin_amdgcn_global_load_lds(
      (const __attribute__((address_space(1))) void*)g,
      (__attribute__((address_space(3))) void*)l, 16, 0, 0);
}

// ---- shared 32x32 transpose-cast tile body ----
__device__ __forceinline__ void tc_tile(const float* __restrict__ inp, int C,
                                        unsigned short* __restrict__ op, int R,
                                        int c0, int r0, float (*tile)[33],
                                        int interleave, int s) {
  int tx = threadIdx.x & 31, ty = threadIdx.x >> 5;
#pragma unroll
  for (int j = 0; j < 4; j++)
    tile[ty + j * 8][tx] = inp[(size_t)(r0 + ty + j * 8) * C + c0 + tx];
  __syncthreads();
  int c = threadIdx.x >> 3, q = threadIdx.x & 7;
  int h = c0 + c;
  int orow = interleave ? (32 * (h >> 4) + 16 * s + (h & 15)) : h;
  ushort4 u;
  u.x = f2bf(tile[q * 4 + 0][c]); u.y = f2bf(tile[q * 4 + 1][c]);
  u.z = f2bf(tile[q * 4 + 2][c]); u.w = f2bf(tile[q * 4 + 3][c]);
  *(ushort4*)&op[(size_t)orow * R + r0 + q * 4] = u;
}

// ==== K1: fused gating (+X cast, blocks 0..255) + W13t transpose-cast ====
__global__ __launch_bounds__(256) void prep_kernel(
    const float* __restrict__ X, const float* __restrict__ Wg,
    const float* __restrict__ bg, const float* __restrict__ W1,
    const float* __restrict__ W3, unsigned short* __restrict__ Xb,
    unsigned short* __restrict__ W13t, int* __restrict__ topk_pack,
    float* __restrict__ topk_w, int* __restrict__ blkcnt) {
  __shared__ float smem[NE * DIM + NE];
  const int b = blockIdx.x;
  if (b >= 256) {
    int i = b - 256;
    int z = i >> 11, rem = i & 2047;
    int e = z & 7, s = z >> 3;
    tc_tile((s ? W3 : W1) + (size_t)e * DIM * HID, HID,
            W13t + (size_t)e * 2 * HID * DIM, DIM,
            (rem & 63) * 32, (rem >> 6) * 32, (float(*)[33])smem, 1, s);
    return;
  }
  float (*wgs)[DIM] = (float(*)[DIM])smem;
  int* hist = (int*)&smem[NE * DIM];
  const int tid = threadIdx.x;
  for (int d = tid; d < DIM; d += 256) {
#pragma unroll
    for (int e = 0; e < NE; e++) wgs[e][d] = Wg[d * NE + e];
  }
  if (tid < NE) hist[tid] = 0;
  __syncthreads();
  const int wave = tid >> 6, lane = tid & 63;
  for (int tk = wave; tk < 16; tk += 4) {
    const int t = b * 16 + tk;
    const float* xr = X + (size_t)t * DIM;
    {
      const float4* xp = (const float4*)(xr + lane * 16);
      float4 v0 = xp[0], v1 = xp[1], v2 = xp[2], v3 = xp[3];
      uint4 w0, w1;
      w0.x = f2bf(v0.x) | ((unsigned)f2bf(v0.y) << 16);
      w0.y = f2bf(v0.z) | ((unsigned)f2bf(v0.w) << 16);
      w0.z = f2bf(v1.x) | ((unsigned)f2bf(v1.y) << 16);
      w0.w = f2bf(v1.z) | ((unsigned)f2bf(v1.w) << 16);
      w1.x = f2bf(v2.x) | ((unsigned)f2bf(v2.y) << 16);
      w1.y = f2bf(v2.z) | ((unsigned)f2bf(v2.w) << 16);
      w1.z = f2bf(v3.x) | ((unsigned)f2bf(v3.y) << 16);
      w1.w = f2bf(v3.z) | ((unsigned)f2bf(v3.w) << 16);
      uint4* op2 = (uint4*)(Xb + (size_t)t * DIM + lane * 16);
      op2[0] = w0; op2[1] = w1;
    }
    float acc[NE];
#pragma unroll
    for (int e = 0; e < NE; e++) acc[e] = 0.f;
#pragma unroll
    for (int j = 0; j < 16; j++) {
      float xv = xr[lane + j * 64];
#pragma unroll
      for (int e = 0; e < NE; e++) acc[e] += xv * wgs[e][lane + j * 64];
    }
#pragma unroll
    for (int e = 0; e < NE; e++) {
#pragma unroll
      for (int off = 32; off > 0; off >>= 1) acc[e] += __shfl_xor(acc[e], off, 64);
    }
    if (lane == 0) {
      float p[NE];
      float mx = -1e30f;
#pragma unroll
      for (int e = 0; e < NE; e++) { p[e] = acc[e] + bg[e]; mx = fmaxf(mx, p[e]); }
      float sum = 0.f;
#pragma unroll
      for (int e = 0; e < NE; e++) { p[e] = expf(p[e] - mx); sum += p[e]; }
      float inv = 1.f / sum;
#pragma unroll
      for (int e = 0; e < NE; e++) p[e] *= inv;
      int i1 = 0; float v1 = p[0];
#pragma unroll
      for (int e = 1; e < NE; e++) if (p[e] >= v1) { v1 = p[e]; i1 = e; }
      int i2 = (i1 == 0) ? 1 : 0; float v2 = p[i2];
#pragma unroll
      for (int e = 0; e < NE; e++) {
        if (e == i1) continue;
        if (p[e] >= v2 && e != i2) { v2 = p[e]; i2 = e; }
      }
      topk_pack[t] = i1 | (i2 << 4);
      topk_w[t * 2 + 0] = v1; topk_w[t * 2 + 1] = v2;
      atomicAdd(&hist[i1], 1); atomicAdd(&hist[i2], 1);
    }
  }
  __syncthreads();
  if (tid < NE) blkcnt[b * NE + tid] = hist[tid];
}

// ------- scatter with integrated prefix; tp (BM=128) and tpB (BM=64) -------
__global__ void scatter_kernel(const int* __restrict__ blkcnt,
                               const int* __restrict__ topk_pack,
                               int* __restrict__ counts, int* __restrict__ row_start,
                               int* __restrict__ tp, int* __restrict__ tpB,
                               int* __restrict__ list) {
  __shared__ int lofs[NE];
  const int lane = threadIdx.x;   // 64
  const int myb = blockIdx.x;     // 256
  int s = 0, t = 0, t2 = 0;
#pragma unroll
  for (int e = 0; e < NE; e++) {
    int tote = 0, pre = 0;
#pragma unroll
    for (int j = 0; j < 4; j++) {
      int b = lane * 4 + j;
      int c = blkcnt[b * NE + e];
      tote += c;
      if (b < myb) pre += c;
    }
#pragma unroll
    for (int off = 32; off > 0; off >>= 1) {
      tote += __shfl_xor(tote, off, 64);
      pre  += __shfl_xor(pre,  off, 64);
    }
    if (lane == 0) lofs[e] = s + pre;
    if (myb == 0 && lane == 0) {
      counts[e] = tote; row_start[e] = s; tp[e] = t; tpB[e] = t2;
    }
    s += tote; t += (tote + 127) >> 7; t2 += (tote + 63) >> 6;
  }
  if (myb == 0 && lane == 0) { tp[NE] = t; tpB[NE] = t2; }
  __syncthreads();
  if (lane < 16) {
    int tok = myb * 16 + lane;
    int pk = topk_pack[tok];
    int e1 = pk & 15, e2 = (pk >> 4) & 15;
    int p1 = atomicAdd(&lofs[e1], 1); list[p1] = tok << 1;
    int p2 = atomicAdd(&lofs[e2], 1); list[p2] = (tok << 1) | 1;
  }
}

// ==== stage A (proven 128x128 m97 loop) + trailing W2t/Wf cast blocks ====
#define FFNA_BLKS 2304
#define W2T_BLKS  16384
__global__ __launch_bounds__(256, 3) void ffn_a_kernel(
    const unsigned short* __restrict__ Xb,
    const unsigned short* __restrict__ W13t,
    const float* __restrict__ b1, const float* __restrict__ b3,
    const float* __restrict__ W2, const float* __restrict__ Wf,
    unsigned short* __restrict__ W2t, unsigned short* __restrict__ Wft,
    const int* __restrict__ counts, const int* __restrict__ row_start,
    const int* __restrict__ tp, const int* __restrict__ list,
    unsigned short* __restrict__ h_buf) {
  __shared__ unsigned short As[128 * 64];
  __shared__ unsigned short Bs[128 * 64];
  const int bid = blockIdx.x;
  if (bid >= FFNA_BLKS) {
    int i = bid - FFNA_BLKS;
    if (i < W2T_BLKS) {
      int z = i >> 11, rem = i & 2047;
      tc_tile(W2 + (size_t)z * HID * OUTD, OUTD, W2t + (size_t)z * OUTD * HID, HID,
              (rem & 31) * 32, (rem >> 5) * 32, (float(*)[33])As, 0, 0);
    } else {
      int i2 = i - W2T_BLKS;
      tc_tile(Wf, OUTD, Wft, DIM, (i2 & 31) * 32, (i2 >> 5) * 32,
              (float(*)[33])As, 0, 0);
    }
    return;
  }
  const int by = bid >> 5;
  if (by >= tp[NE]) return;
  int e = 0;
#pragma unroll
  for (int k = 1; k < NE; k++) if (by >= tp[k]) e = k;
  const int ne = counts[e], rs = row_start[e];
  const int m0 = (by - tp[e]) * 128;
  const int n0 = (bid & 31) * 128;

  const int tid = threadIdx.x;
  const int wave = tid >> 6, lane = tid & 63;
  const int lr = lane & 15, lk = lane >> 4;
  const int wm = (wave >> 1) * 64, wn = (wave & 1) * 64;

  const int scs = ((lane & 7) ^ (lane >> 3)) * 8;
  const unsigned short* asrc[4];
  const unsigned short* bsrc[4];
#pragma unroll
  for (int i = 0; i < 4; i++) {
    int sr = (wave * 4 + i) * 8 + (lane >> 3);
    int rr = m0 + sr; if (rr >= ne) rr = m0;
    int tok = list[rs + rr] >> 1;
    asrc[i] = Xb + (size_t)tok * DIM + scs;
    bsrc[i] = W13t + ((size_t)e * 2 * HID + n0 + sr) * DIM + scs;
  }

  f32x4 acc[4][4];
  const f32x4 zero = {0.f, 0.f, 0.f, 0.f};
#pragma unroll
  for (int m = 0; m < 4; m++)
#pragma unroll
    for (int n = 0; n < 4; n++) acc[m][n] = zero;

  const int sx = lr & 7;

  for (int k0 = 0; k0 < DIM; k0 += 64) {
#pragma unroll
    for (int i = 0; i < 4; i++) {
      gload16(asrc[i] + k0, &As[(wave * 4 + i) * 512]);
      gload16(bsrc[i] + k0, &Bs[(wave * 4 + i) * 512]);
    }
    __syncthreads();
#pragma unroll
    for (int kk = 0; kk < 2; kk++) {
      const int sl = ((kk * 4 + lk) ^ sx) * 8;
      bf16x8 a[4], b[4];
#pragma unroll
      for (int m = 0; m < 4; m++)
        a[m] = *(const bf16x8*)&As[(wm + m * 16 + lr) * 64 + sl];
#pragma unroll
      for (int n = 0; n < 4; n++)
        b[n] = *(const bf16x8*)&Bs[(wn + n * 16 + lr) * 64 + sl];
#pragma unroll
      for (int m = 0; m < 4; m++)
#pragma unroll
        for (int n = 0; n < 4; n++)
          acc[m][n] = __builtin_amdgcn_mfma_f32_16x16x32_bf16(a[m], b[n], acc[m][n], 0, 0, 0);
    }
    __syncthreads();
  }

  const int hq = (n0 + wn) >> 5;
#pragma unroll
  for (int g = 0; g < 2; g++) {
    int h = (hq + g) * 16 + lr;
    float b1v = b1[e * HID + h];
    float b3v = b3[e * HID + h];
#pragma unroll
    for (int m = 0; m < 4; m++) {
#pragma unroll
      for (int j = 0; j < 4; j++) {
        int rr = m0 + wm + m * 16 + lk * 4 + j;
        if (rr < ne) {
          float h1 = acc[m][2 * g][j] + b1v;
          float h3 = acc[m][2 * g + 1][j] + b3v;
          float v = h1 * h3;
          h_buf[(size_t)(rs + rr) * HID + h] = f2bf(v / (1.f + expf(-v)));
        }
      }
    }
  }
}

// ==== stage B: 64x128 tiles (wave-tile 32x64), BK=64, 4 blocks/CU, bf16 out ====
__global__ __launch_bounds__(256, 4) void ffn_b_kernel(
    const unsigned short* __restrict__ h_buf,
    const unsigned short* __restrict__ W2t,
    const float* __restrict__ b2,
    const int* __restrict__ counts, const int* __restrict__ row_start,
    const int* __restrict__ tpB, const int* __restrict__ list,
    const float* __restrict__ topk_w, unsigned short* __restrict__ ob) {
  __shared__ unsigned short As[64 * 64];    // 8KB
  __shared__ unsigned short Bs[128 * 64];   // 16KB
  const int by = blockIdx.y;
  if (by >= tpB[NE]) return;
  int e = 0;
#pragma unroll
  for (int k = 1; k < NE; k++) if (by >= tpB[k]) e = k;
  const int ne = counts[e], rs = row_start[e];
  const int m0 = (by - tpB[e]) * 64;
  const int n0 = blockIdx.x * 128;

  const int tid = threadIdx.x;
  const int wave = tid >> 6, lane = tid & 63;
  const int lr = lane & 15, lk = lane >> 4;
  const int wm = (wave & 1) * 32, wn = (wave >> 1) * 64;

  const int scs = ((lane & 7) ^ (lane >> 3)) * 8;
  const unsigned short* asrc[2];
  const unsigned short* bsrc[4];
#pragma unroll
  for (int i = 0; i < 2; i++) {
    int sr = (wave * 2 + i) * 8 + (lane >> 3);              // 0..63
    asrc[i] = h_buf + (size_t)(rs + m0 + sr) * HID + scs;   // padded rows, in-bounds
  }
#pragma unroll
  for (int i = 0; i < 4; i++) {
    int sr = (wave * 4 + i) * 8 + (lane >> 3);              // 0..127
    bsrc[i] = W2t + ((size_t)e * OUTD + n0 + sr) * HID + scs;
  }

  f32x4 acc[2][4];
  const f32x4 zero = {0.f, 0.f, 0.f, 0.f};
#pragma unroll
  for (int m = 0; m < 2; m++)
#pragma unroll
    for (int n = 0; n < 4; n++) acc[m][n] = zero;

  const int sx = lr & 7;

  for (int k0 = 0; k0 < HID; k0 += 64) {
#pragma unroll
    for (int i = 0; i < 2; i++)
      gload16(asrc[i] + k0, &As[(wave * 2 + i) * 512]);
#pragma unroll
    for (int i = 0; i < 4; i++)
      gload16(bsrc[i] + k0, &Bs[(wave * 4 + i) * 512]);
    __syncthreads();
#pragma unroll
    for (int kk = 0; kk < 2; kk++) {
      const int sl = ((kk * 4 + lk) ^ sx) * 8;
      bf16x8 a[2], b[4];
#pragma unroll
      for (int m = 0; m < 2; m++)
        a[m] = *(const bf16x8*)&As[(wm + m * 16 + lr) * 64 + sl];
#pragma unroll
      for (int n = 0; n < 4; n++)
        b[n] = *(const bf16x8*)&Bs[(wn + n * 16 + lr) * 64 + sl];
#pragma unroll
      for (int m = 0; m < 2; m++)
#pragma unroll
        for (int n = 0; n < 4; n++)
          acc[m][n] = __builtin_amdgcn_mfma_f32_16x16x32_bf16(a[m], b[n], acc[m][n], 0, 0, 0);
    }
    __syncthreads();
  }

#pragma unroll
  for (int n = 0; n < 4; n++) {
    int col = n0 + wn + n * 16 + lr;
    float b2v = b2[e * OUTD + col];
#pragma unroll
    for (int m = 0; m < 2; m++) {
#pragma unroll
      for (int j = 0; j < 4; j++) {
        int rr = m0 + wm + m * 16 + lk * 4 + j;
        if (rr < ne) {
          int entry = list[rs + rr];
          float w = topk_w[entry];
          ob[(size_t)entry * OUTD + col] = f2bf(w * (acc[m][n][j] + b2v));
        }
      }
    }
  }
}

// ---- final: 64x128 tiles (wave-tile 32x64): out = (ob0 + ob1) @ Wf + bf ----
__global__ __launch_bounds__(256, 4) void final_kernel(
    const unsigned short* __restrict__ ob, const unsigned short* __restrict__ Wft,
    const float* __restrict__ bfv, float* __restrict__ out) {
  const int bid = blockIdx.x;               // 512 = 8 n x 64 m
  const int n0 = (bid & 7) * 128;
  const int m0 = (bid >> 3) * 64;

  __shared__ unsigned short As[64 * 64];    // 8KB
  __shared__ unsigned short Bs[128 * 64];   // 16KB

  const int tid = threadIdx.x;
  const int wave = tid >> 6, lane = tid & 63;
  const int lrow = lane >> 3;
  const int lcol = (lane & 7) * 8;

  const unsigned short* bsrc[4];
#pragma unroll
  for (int i = 0; i < 4; i++) {
    int sr = (wave * 4 + i) * 8 + lrow;     // 0..127
    bsrc[i] = Wft + (size_t)(n0 + sr) * DIM + lcol;
  }

  const int wm = (wave & 1) * 32, wn = (wave >> 1) * 64;
  const int lr = lane & 15, lk = lane >> 4;

  f32x4 acc[2][4];
  const f32x4 zero = {0.f, 0.f, 0.f, 0.f};
#pragma unroll
  for (int m = 0; m < 2; m++)
#pragma unroll
    for (int n = 0; n < 4; n++) acc[m][n] = zero;

  for (int k0 = 0; k0 < DIM; k0 += 64) {
#pragma unroll
    for (int g = 0; g < 4; g++) {
      int idx = g * 256 + tid;              // 0..1023
      int r = idx >> 4;                     // 0..63
      int c4 = (idx & 15) * 4;
      ushort4 a0 = *(const ushort4*)&ob[((size_t)(m0 + r) * 2) * OUTD + k0 + c4];
      ushort4 a1 = *(const ushort4*)&ob[((size_t)(m0 + r) * 2 + 1) * OUTD + k0 + c4];
      ushort4 u;
      u.x = f2bf(b2f(a0.x) + b2f(a1.x)); u.y = f2bf(b2f(a0.y) + b2f(a1.y));
      u.z = f2bf(b2f(a0.z) + b2f(a1.z)); u.w = f2bf(b2f(a0.w) + b2f(a1.w));
      *(ushort4*)&As[r * 64 + c4] = u;
    }
#pragma unroll
    for (int i = 0; i < 4; i++) gload16(bsrc[i] + k0, &Bs[(wave * 4 + i) * 512]);
    __syncthreads();
#pragma unroll
    for (int kk = 0; kk < 2; kk++) {
      bf16x8 a[2], b[4];
#pragma unroll
      for (int m = 0; m < 2; m++)
        a[m] = *(const bf16x8*)&As[(wm + m * 16 + lr) * 64 + kk * 32 + lk * 8];
#pragma unroll
      for (int n = 0; n < 4; n++)
        b[n] = *(const bf16x8*)&Bs[(wn + n * 16 + lr) * 64 + kk * 32 + lk * 8];
#pragma unroll
      for (int m = 0; m < 2; m++)
#pragma unroll
        for (int n = 0; n < 4; n++)
          acc[m][n] = __builtin_amdgcn_mfma_f32_16x16x32_bf16(a[m], b[n], acc[m][n], 0, 0, 0);
    }
    __syncthreads();
  }

#pragma unroll
  for (int n = 0; n < 4; n++) {
    int col = n0 + wn + n * 16 + lr;
    float bv = bfv[col];
#pragma unroll
    for (int m = 0; m < 2; m++) {
#pragma unroll
      for (int j = 0; j < 4; j++) {
        int r = m0 + wm + m * 16 + lk * 4 + j;
        out[(size_t)r * OUTD + col] = acc[m][n][j] + bv;
      }
    }
  }
}

extern "C" void kernel_launch(void* const* d_in, const int* in_sizes, int n_in,
                              void* d_out, int out_size, void* d_ws, size_t ws_size,
                              hipStream_t stream) {
  const float* X   = (const float*)d_in[0];
  const float* W1  = (const float*)d_in[1];
  const float* b1  = (const float*)d_in[2];
  const float* W3  = (const float*)d_in[3];
  const float* b3  = (const float*)d_in[4];
  const float* W2  = (const float*)d_in[5];
  const float* b2  = (const float*)d_in[6];
  const float* Wg  = (const float*)d_in[7];
  const float* bg  = (const float*)d_in[8];
  const float* Wf  = (const float*)d_in[9];
  const float* bfv = (const float*)d_in[10];
  float* out = (float*)d_out;

  char* p = (char*)d_ws;
  auto alloc = [&](size_t bytes) { char* r = p; p += (bytes + 255) & ~(size_t)255; return r; };
  unsigned short* Xb   = (unsigned short*)alloc((size_t)NTOK * DIM * 2);
  unsigned short* W13t = (unsigned short*)alloc((size_t)NE * 2 * HID * DIM * 2);
  unsigned short* W2t  = (unsigned short*)alloc((size_t)NE * OUTD * HID * 2);
  unsigned short* Wft  = (unsigned short*)alloc((size_t)OUTD * DIM * 2);
  unsigned short* hbuf = (unsigned short*)alloc((size_t)(NTOK * 2 + 256) * HID * 2);
  unsigned short* ob   = (unsigned short*)alloc((size_t)NTOK * 2 * OUTD * 2);
  int* topk_pack       = (int*)alloc(NTOK * 4);
  float* topk_w        = (float*)alloc(NTOK * 2 * 4);
  int* counts          = (int*)alloc(NE * 4);
  int* row_start       = (int*)alloc(NE * 4);
  int* tp              = (int*)alloc((NE + 1) * 4);
  int* tpB             = (int*)alloc((NE + 1) * 4);
  int* blkcnt          = (int*)alloc(256 * NE * 4);
  int* list            = (int*)alloc(NTOK * 2 * 4);

  // K1: gating (256) + W13t cast (32768)
  prep_kernel<<<256 + 32768, 256, 0, stream>>>(
      X, Wg, bg, W1, W3, Xb, W13t, topk_pack, topk_w, blkcnt);
  // K2: prefix + scatter
  scatter_kernel<<<256, 64, 0, stream>>>(blkcnt, topk_pack, counts, row_start,
                                         tp, tpB, list);
  // K3: ffn_a GEMM (2304) + W2t cast (16384) + Wf cast (1024)
  ffn_a_kernel<<<FFNA_BLKS + W2T_BLKS + 1024, 256, 0, stream>>>(
      Xb, W13t, b1, b3, W2, Wf, W2t, Wft, counts, row_start, tp, list, hbuf);
  // K4: ffn_b, BM=64 -> max tiles = sum ceil(ne/64) <= 128+7 = 135 -> 136
  ffn_b_kernel<<<dim3(OUTD / 128, 136), 256, 0, stream>>>(
      hbuf, W2t, b2, counts, row_start, tpB, list, topk_w, ob);
  // K5: final, 64x128 tiles -> 8 x 64 = 512 blocks
  final_kernel<<<512, 256, 0, stream>>>(ob, Wft, bfv, out);
}